// Round 1
// baseline (1908.371 us; speedup 1.0000x reference)
//
#include <hip/hip_runtime.h>
#include <math.h>

// Problem constants (fixed by setup_inputs)
#define BB 2
#define TT 1024
#define CC 1024
#define HH 16
#define HD 64
#define MM (BB*TT)   // 2048 rows

// ---------------------------------------------------------------- RoPE tables
// cos/sin of t * 10000^(-d/32), d in [0,32). Tables are duplicated across the
// two halves in the reference, so we only store [T][32].
__global__ void rope_table_kernel(float* __restrict__ cosT, float* __restrict__ sinT) {
    int t = blockIdx.x;
    int d = threadIdx.x;  // 0..31
    double inv = pow(10000.0, -((double)d) / 32.0);
    double ang = (double)t * inv;
    cosT[t * 32 + d] = (float)cos(ang);
    sinT[t * 32 + d] = (float)sin(ang);
}

// ---------------------------------------------------------------- LayerNorm
__global__ __launch_bounds__(256) void ln_kernel(const float* __restrict__ x,
                                                 const float* __restrict__ g,
                                                 const float* __restrict__ bta,
                                                 float* __restrict__ out) {
    int row = blockIdx.x;
    const float* xr = x + (size_t)row * CC;
    float4 v = reinterpret_cast<const float4*>(xr)[threadIdx.x];
    float s  = v.x + v.y + v.z + v.w;
    float sq = v.x*v.x + v.y*v.y + v.z*v.z + v.w*v.w;
    #pragma unroll
    for (int off = 32; off >= 1; off >>= 1) {
        s  += __shfl_down(s, off);
        sq += __shfl_down(sq, off);
    }
    __shared__ float ls[4], lsq[4];
    int wave = threadIdx.x >> 6, lane = threadIdx.x & 63;
    if (lane == 0) { ls[wave] = s; lsq[wave] = sq; }
    __syncthreads();
    s  = ls[0] + ls[1] + ls[2] + ls[3];
    sq = lsq[0] + lsq[1] + lsq[2] + lsq[3];
    float mean = s * (1.0f / CC);
    float var  = sq * (1.0f / CC) - mean * mean;
    float rstd = rsqrtf(var + 1e-5f);
    float4 gv = reinterpret_cast<const float4*>(g)[threadIdx.x];
    float4 bv = reinterpret_cast<const float4*>(bta)[threadIdx.x];
    float4 o;
    o.x = (v.x - mean) * rstd * gv.x + bv.x;
    o.y = (v.y - mean) * rstd * gv.y + bv.y;
    o.z = (v.z - mean) * rstd * gv.z + bv.z;
    o.w = (v.w - mean) * rstd * gv.w + bv.w;
    reinterpret_cast<float4*>(out + (size_t)row * CC)[threadIdx.x] = o;
}

// ---------------------------------------------------------------- GEMM (fp32)
__device__ __forceinline__ float gelu_tanh(float x) {
    float x3 = x * x * x;
    return 0.5f * x * (1.0f + tanhf(0.7978845608028654f * (x + 0.044715f * x3)));
}

// out[M,N] = act(A[M,K] @ W[K,N] + bias) (+ res). 64x64 tile, 256 threads, 4x4/thread.
__global__ __launch_bounds__(256) void gemm_f32(const float* __restrict__ A,
                                                const float* __restrict__ W,
                                                const float* __restrict__ bias,
                                                const float* __restrict__ res,
                                                float* __restrict__ out,
                                                int N, int K, int act) {
    __shared__ __align__(16) float As[16][68];
    __shared__ __align__(16) float Bs[16][68];
    int tid = threadIdx.x;
    int row0 = blockIdx.y * 64, col0 = blockIdx.x * 64;
    int tx = tid & 15, ty = tid >> 4;
    int am = tid >> 2, ak = (tid & 3) * 4;   // A loader: row am, k-offset ak (transpose into LDS)
    int bk = tid >> 4, bn = (tid & 15) * 4;  // B loader
    float acc[4][4] = {};
    for (int k0 = 0; k0 < K; k0 += 16) {
        float4 a4 = *reinterpret_cast<const float4*>(A + (size_t)(row0 + am) * K + k0 + ak);
        float4 b4 = *reinterpret_cast<const float4*>(W + (size_t)(k0 + bk) * N + col0 + bn);
        __syncthreads();
        As[ak + 0][am] = a4.x; As[ak + 1][am] = a4.y;
        As[ak + 2][am] = a4.z; As[ak + 3][am] = a4.w;
        *reinterpret_cast<float4*>(&Bs[bk][bn]) = b4;
        __syncthreads();
        #pragma unroll
        for (int kk = 0; kk < 16; ++kk) {
            float4 av = *reinterpret_cast<const float4*>(&As[kk][ty * 4]);
            float4 bv = *reinterpret_cast<const float4*>(&Bs[kk][tx * 4]);
            float a[4] = {av.x, av.y, av.z, av.w};
            float b[4] = {bv.x, bv.y, bv.z, bv.w};
            #pragma unroll
            for (int i = 0; i < 4; ++i)
                #pragma unroll
                for (int j = 0; j < 4; ++j) acc[i][j] += a[i] * b[j];
        }
    }
    int rb = row0 + ty * 4, cb = col0 + tx * 4;
    float4 bi = *reinterpret_cast<const float4*>(bias + cb);
    #pragma unroll
    for (int i = 0; i < 4; ++i) {
        size_t o = (size_t)(rb + i) * N + cb;
        float4 v = {acc[i][0] + bi.x, acc[i][1] + bi.y, acc[i][2] + bi.z, acc[i][3] + bi.w};
        if (act == 1) { v.x = gelu_tanh(v.x); v.y = gelu_tanh(v.y); v.z = gelu_tanh(v.z); v.w = gelu_tanh(v.w); }
        if (res) {
            float4 rv = *reinterpret_cast<const float4*>(res + o);
            v.x += rv.x; v.y += rv.y; v.z += rv.z; v.w += rv.w;
        }
        *reinterpret_cast<float4*>(out + o) = v;
    }
}

// ------------------------------------------------- head pack (+ optional elu+1)
// dst[b][h][t][d] = f(src[(b*T+t)*rowstride + coloff + h*64 + d])
__global__ void pack_kernel(const float* __restrict__ src, int rowstride, int coloff,
                            float* __restrict__ dst, int applyElu) {
    int idx = blockIdx.x * blockDim.x + threadIdx.x;  // 0 .. 2M-1
    int d = idx & 63;
    int t = (idx >> 6) & 1023;
    int h = (idx >> 16) & 15;
    int b = idx >> 20;
    float v = src[(size_t)(b * TT + t) * rowstride + coloff + h * HD + d];
    if (applyElu) v = (v > 0.0f) ? v + 1.0f : expf(v);  // elu(x)+1
    dst[idx] = v;
}

// Ksum[bh][d] = sum_t Kf[bh][t][d]
__global__ void ksum_kernel(const float* __restrict__ Kf, float* __restrict__ Ksum) {
    int bh = blockIdx.x;
    int lane = threadIdx.x & 63;
    int w = threadIdx.x >> 6;
    const float* base = Kf + (size_t)bh * TT * HD;
    float s = 0.f;
    for (int t = w; t < TT; t += 4) s += base[t * HD + lane];
    __shared__ float ls[4][64];
    ls[w][lane] = s;
    __syncthreads();
    if (threadIdx.x < 64)
        Ksum[bh * HD + lane] = ls[0][lane] + ls[1][lane] + ls[2][lane] + ls[3][lane];
}

// den[bh][t] = Qf[bh][t][:] . Ksum[bh][:]
__global__ void denom_kernel(const float* __restrict__ Qf, const float* __restrict__ Ksum,
                             float* __restrict__ den) {
    int bh = blockIdx.x >> 8;        // 256 blocks per bh, 4 rows per block
    int tblk = blockIdx.x & 255;
    int w = threadIdx.x >> 6, lane = threadIdx.x & 63;
    int t = tblk * 4 + w;
    float p = Qf[((size_t)bh * TT + t) * HD + lane] * Ksum[bh * HD + lane];
    #pragma unroll
    for (int off = 32; off >= 1; off >>= 1) p += __shfl_down(p, off);
    if (lane == 0) den[bh * TT + t] = p;
}

// In-place RoPE on a [B*H][T][64] buffer
__global__ void rope_kernel(float* __restrict__ buf, const float* __restrict__ cosT,
                            const float* __restrict__ sinT) {
    int idx = blockIdx.x * blockDim.x + threadIdx.x;  // 0 .. 1M-1
    int d = idx & 31;
    int t = (idx >> 5) & 1023;
    int bh = idx >> 15;
    float c = cosT[t * 32 + d], s = sinT[t * 32 + d];
    size_t base = ((size_t)bh * TT + t) * HD;
    float lo = buf[base + d], hi = buf[base + d + 32];
    buf[base + d]      = lo * c - hi * s;
    buf[base + d + 32] = hi * c + lo * s;
}

// ------------------------------------------------------- fused linear attention
// Y[bh][t][:] = ( sum_{s (<=t if causal)} (Qr[t].Kr[s]) * V[s][:] ) / den[bh][t]
template <bool CAUSAL>
__global__ __launch_bounds__(256) void attn_kernel(const float* __restrict__ Qr,
                                                   const float* __restrict__ Kr,
                                                   const float* __restrict__ V,
                                                   const float* __restrict__ den,
                                                   float* __restrict__ Y) {
    __shared__ __align__(16) float Qs[64][68];
    __shared__ __align__(16) float Ks[64][68];
    __shared__ __align__(16) float Vs[64][68];
    __shared__ __align__(16) float Sc[64][68];
    int bh = blockIdx.y;
    int t0 = blockIdx.x * 64;
    int tid = threadIdx.x;
    const float* Qb = Qr + ((size_t)bh * TT + t0) * HD;
    #pragma unroll
    for (int i = 0; i < 4; ++i) {
        int f = tid + i * 256;               // float4 index 0..1023
        int r = f >> 4, c4 = (f & 15) * 4;
        *reinterpret_cast<float4*>(&Qs[r][c4]) =
            *reinterpret_cast<const float4*>(Qb + r * HD + c4);
    }
    float acc[16] = {};
    int tl = tid >> 2;   // row within tile
    int qg = tid & 3;    // quarter
    int ntiles = CAUSAL ? (blockIdx.x + 1) : (TT / 64);
    for (int st = 0; st < ntiles; ++st) {
        int s0 = st * 64;
        __syncthreads();  // protect Ks/Vs/Sc from previous iteration readers
        const float* Kb = Kr + ((size_t)bh * TT + s0) * HD;
        const float* Vb = V  + ((size_t)bh * TT + s0) * HD;
        #pragma unroll
        for (int i = 0; i < 4; ++i) {
            int f = tid + i * 256;
            int r = f >> 4, c4 = (f & 15) * 4;
            *reinterpret_cast<float4*>(&Ks[r][c4]) =
                *reinterpret_cast<const float4*>(Kb + r * HD + c4);
            *reinterpret_cast<float4*>(&Vs[r][c4]) =
                *reinterpret_cast<const float4*>(Vb + r * HD + c4);
        }
        __syncthreads();
        // scores: thread handles row tl, cols qg*16..+15
        #pragma unroll
        for (int j = 0; j < 16; ++j) {
            int sl = qg * 16 + j;
            float dot = 0.f;
            #pragma unroll
            for (int d4 = 0; d4 < 16; ++d4) {
                float4 q = *reinterpret_cast<const float4*>(&Qs[tl][d4 * 4]);
                float4 k = *reinterpret_cast<const float4*>(&Ks[sl][d4 * 4]);
                dot += q.x * k.x + q.y * k.y + q.z * k.z + q.w * k.w;
            }
            if (CAUSAL && (s0 + sl > t0 + tl)) dot = 0.f;
            Sc[tl][sl] = dot;
        }
        __syncthreads();
        // accumulate: thread handles row tl, d = qg*16..+15
        int d0 = qg * 16;
        for (int sl = 0; sl < 64; ++sl) {
            float w = Sc[tl][sl];
            #pragma unroll
            for (int i4 = 0; i4 < 4; ++i4) {
                float4 v = *reinterpret_cast<const float4*>(&Vs[sl][d0 + i4 * 4]);
                acc[i4 * 4 + 0] += w * v.x;
                acc[i4 * 4 + 1] += w * v.y;
                acc[i4 * 4 + 2] += w * v.z;
                acc[i4 * 4 + 3] += w * v.w;
            }
        }
    }
    float inv = 1.0f / den[bh * TT + t0 + tl];
    float* Yb = Y + ((size_t)bh * TT + t0 + tl) * HD + qg * 16;
    #pragma unroll
    for (int i4 = 0; i4 < 4; ++i4) {
        float4 o = {acc[i4 * 4 + 0] * inv, acc[i4 * 4 + 1] * inv,
                    acc[i4 * 4 + 2] * inv, acc[i4 * 4 + 3] * inv};
        reinterpret_cast<float4*>(Yb)[i4] = o;
    }
}

// [B,H,T,hd] -> [B,T,C]
__global__ void unpack_kernel(const float* __restrict__ Y, float* __restrict__ out) {
    int idx = blockIdx.x * blockDim.x + threadIdx.x;  // 0 .. 2M-1 (bhtd layout)
    int d = idx & 63;
    int t = (idx >> 6) & 1023;
    int h = (idx >> 16) & 15;
    int b = idx >> 20;
    out[(size_t)(b * TT + t) * CC + h * HD + d] = Y[idx];
}

// ---------------------------------------------------------------- launch
extern "C" void kernel_launch(void* const* d_in, const int* in_sizes, int n_in,
                              void* d_out, int out_size, void* d_ws, size_t ws_size,
                              hipStream_t stream) {
    const float* x        = (const float*)d_in[0];
    const float* memory   = (const float*)d_in[1];
    const float* ln1_g    = (const float*)d_in[2];
    const float* ln1_b    = (const float*)d_in[3];
    const float* sa_qkv_w = (const float*)d_in[4];
    const float* sa_qkv_b = (const float*)d_in[5];
    const float* sa_pr_w  = (const float*)d_in[6];
    const float* sa_pr_b  = (const float*)d_in[7];
    const float* ln2_g    = (const float*)d_in[8];
    const float* ln2_b    = (const float*)d_in[9];
    const float* ca_q_w   = (const float*)d_in[10];
    const float* ca_q_b   = (const float*)d_in[11];
    const float* ca_kv_w  = (const float*)d_in[12];
    const float* ca_kv_b  = (const float*)d_in[13];
    const float* ca_pr_w  = (const float*)d_in[14];
    const float* ca_pr_b  = (const float*)d_in[15];
    const float* ln3_g    = (const float*)d_in[16];
    const float* ln3_b    = (const float*)d_in[17];
    const float* fc_w     = (const float*)d_in[18];
    const float* fc_b     = (const float*)d_in[19];
    const float* fcp_w    = (const float*)d_in[20];
    const float* fcp_b    = (const float*)d_in[21];
    float* out = (float*)d_out;
    float* ws  = (float*)d_ws;

    // ws layout (float offsets)
    float* bigbuf = ws;                       // 8M floats (qkv / q+kv / fc out)
    float* hbuf   = ws + 8388608;             // 2M (LN output)
    float* h2buf  = ws + 10485760;            // 2M (attn out packed)
    float* Qf     = ws + 12582912;            // 2M
    float* Kf     = ws + 14680064;            // 2M
    float* Vb     = ws + 16777216;            // 2M
    float* Yb     = ws + 18874368;            // 2M
    float* Ksum   = ws + 20971520;            // 2048
    float* den    = ws + 20973568;            // 32768
    float* cosT   = ws + 21006336;            // 32768
    float* sinT   = ws + 21039104;            // 32768

    dim3 b256(256);

    rope_table_kernel<<<dim3(TT), dim3(32), 0, stream>>>(cosT, sinT);

    // ---- causal self-attention ----
    ln_kernel<<<dim3(MM), b256, 0, stream>>>(x, ln1_g, ln1_b, hbuf);
    gemm_f32<<<dim3(3072 / 64, MM / 64), b256, 0, stream>>>(hbuf, sa_qkv_w, sa_qkv_b, nullptr, bigbuf, 3072, 1024, 0);
    pack_kernel<<<dim3(8192), b256, 0, stream>>>(bigbuf, 3072, 0,    Qf, 1);
    pack_kernel<<<dim3(8192), b256, 0, stream>>>(bigbuf, 3072, 1024, Kf, 1);
    pack_kernel<<<dim3(8192), b256, 0, stream>>>(bigbuf, 3072, 2048, Vb, 0);
    ksum_kernel<<<dim3(32), b256, 0, stream>>>(Kf, Ksum);
    denom_kernel<<<dim3(8192), b256, 0, stream>>>(Qf, Ksum, den);
    rope_kernel<<<dim3(4096), b256, 0, stream>>>(Qf, cosT, sinT);
    rope_kernel<<<dim3(4096), b256, 0, stream>>>(Kf, cosT, sinT);
    attn_kernel<true><<<dim3(16, 32), b256, 0, stream>>>(Qf, Kf, Vb, den, Yb);
    unpack_kernel<<<dim3(8192), b256, 0, stream>>>(Yb, h2buf);
    gemm_f32<<<dim3(1024 / 64, MM / 64), b256, 0, stream>>>(h2buf, sa_pr_w, sa_pr_b, x, out, 1024, 1024, 0);

    // ---- cross-attention ----
    ln_kernel<<<dim3(MM), b256, 0, stream>>>(out, ln2_g, ln2_b, hbuf);
    gemm_f32<<<dim3(1024 / 64, MM / 64), b256, 0, stream>>>(hbuf, ca_q_w, ca_q_b, nullptr, bigbuf, 1024, 1024, 0);
    gemm_f32<<<dim3(2048 / 64, MM / 64), b256, 0, stream>>>(memory, ca_kv_w, ca_kv_b, nullptr, bigbuf + 2097152, 2048, 1024, 0);
    pack_kernel<<<dim3(8192), b256, 0, stream>>>(bigbuf, 1024, 0, Qf, 1);
    pack_kernel<<<dim3(8192), b256, 0, stream>>>(bigbuf + 2097152, 2048, 0,    Kf, 1);
    pack_kernel<<<dim3(8192), b256, 0, stream>>>(bigbuf + 2097152, 2048, 1024, Vb, 0);
    ksum_kernel<<<dim3(32), b256, 0, stream>>>(Kf, Ksum);
    denom_kernel<<<dim3(8192), b256, 0, stream>>>(Qf, Ksum, den);
    rope_kernel<<<dim3(4096), b256, 0, stream>>>(Qf, cosT, sinT);
    rope_kernel<<<dim3(4096), b256, 0, stream>>>(Kf, cosT, sinT);
    attn_kernel<false><<<dim3(16, 32), b256, 0, stream>>>(Qf, Kf, Vb, den, Yb);
    unpack_kernel<<<dim3(8192), b256, 0, stream>>>(Yb, h2buf);
    gemm_f32<<<dim3(1024 / 64, MM / 64), b256, 0, stream>>>(h2buf, ca_pr_w, ca_pr_b, out, out, 1024, 1024, 0);

    // ---- MLP ----
    ln_kernel<<<dim3(MM), b256, 0, stream>>>(out, ln3_g, ln3_b, hbuf);
    gemm_f32<<<dim3(4096 / 64, MM / 64), b256, 0, stream>>>(hbuf, fc_w, fc_b, nullptr, bigbuf, 4096, 1024, 1);
    gemm_f32<<<dim3(1024 / 64, MM / 64), b256, 0, stream>>>(bigbuf, fcp_w, fcp_b, out, out, 1024, 4096, 0);
}

// Round 2
// 568.412 us; speedup vs baseline: 3.3574x; 3.3574x over previous
//
#include <hip/hip_runtime.h>
#include <math.h>

#define BB 2
#define TT 1024
#define CC 1024
#define HH 16
#define HD 64
#define MM (BB*TT)   // 2048 rows
#define BH (BB*HH)   // 32

typedef unsigned short u16;
typedef unsigned int u32;
typedef short s16x8 __attribute__((ext_vector_type(8)));
typedef float f32x4 __attribute__((ext_vector_type(4)));

__device__ __forceinline__ u16 f2bf(float f) {
    u32 u = __builtin_bit_cast(u32, f);
    u += 0x7fffu + ((u >> 16) & 1u);
    return (u16)(u >> 16);
}
__device__ __forceinline__ float bf2f(u16 h) {
    return __builtin_bit_cast(float, ((u32)h) << 16);
}
__device__ __forceinline__ void gload16(const void* g, void* l) {
    __builtin_amdgcn_global_load_lds((const __attribute__((address_space(1))) u32*)g,
                                     (__attribute__((address_space(3))) u32*)l, 16, 0, 0);
}
__device__ __forceinline__ float gelu_tanh(float x) {
    float x3 = x * x * x;
    return 0.5f * x * (1.0f + tanhf(0.7978845608028654f * (x + 0.044715f * x3)));
}

// ---------------------------------------------------------------- RoPE tables
__global__ void rope_table_kernel(float* __restrict__ cosT, float* __restrict__ sinT) {
    int t = blockIdx.x;
    int d = threadIdx.x;  // 0..31
    double inv = pow(10000.0, -((double)d) / 32.0);
    double ang = (double)t * inv;
    cosT[t * 32 + d] = (float)cos(ang);
    sinT[t * 32 + d] = (float)sin(ang);
}

// ------------------------------------------------- weight transpose fp32->bf16
// in [K][N] -> out [N][K] bf16
__global__ __launch_bounds__(256) void wtrans_kernel(const float* __restrict__ in,
                                                     u16* __restrict__ out, int K, int N) {
    __shared__ float tl[64][65];
    int n0 = blockIdx.x * 64, k0 = blockIdx.y * 64;
    int c = threadIdx.x & 63, r4 = threadIdx.x >> 6;
    #pragma unroll
    for (int i = 0; i < 16; ++i) {
        int r = r4 * 16 + i;
        tl[r][c] = in[(size_t)(k0 + r) * N + n0 + c];
    }
    __syncthreads();
    #pragma unroll
    for (int i = 0; i < 16; ++i) {
        int r = r4 * 16 + i;
        out[(size_t)(n0 + r) * K + k0 + c] = f2bf(tl[c][r]);
    }
}

// fp32 -> bf16 elementwise (memory input)
__global__ __launch_bounds__(256) void f2b_kernel(const float* __restrict__ in, u16* __restrict__ out) {
    int i = blockIdx.x * 256 + threadIdx.x;
    float4 v = reinterpret_cast<const float4*>(in)[i];
    uint2 p;
    p.x = (u32)f2bf(v.x) | ((u32)f2bf(v.y) << 16);
    p.y = (u32)f2bf(v.z) | ((u32)f2bf(v.w) << 16);
    reinterpret_cast<uint2*>(out)[i] = p;
}

// ---------------------------------------------------------------- LayerNorm (fp32 in, bf16 out)
__global__ __launch_bounds__(256) void ln_kernel(const float* __restrict__ x,
                                                 const float* __restrict__ g,
                                                 const float* __restrict__ bta,
                                                 u16* __restrict__ out) {
    int row = blockIdx.x;
    const float* xr = x + (size_t)row * CC;
    float4 v = reinterpret_cast<const float4*>(xr)[threadIdx.x];
    float s  = v.x + v.y + v.z + v.w;
    float sq = v.x*v.x + v.y*v.y + v.z*v.z + v.w*v.w;
    #pragma unroll
    for (int off = 32; off >= 1; off >>= 1) {
        s  += __shfl_down(s, off);
        sq += __shfl_down(sq, off);
    }
    __shared__ float ls[4], lsq[4];
    int wave = threadIdx.x >> 6, lane = threadIdx.x & 63;
    if (lane == 0) { ls[wave] = s; lsq[wave] = sq; }
    __syncthreads();
    s  = ls[0] + ls[1] + ls[2] + ls[3];
    sq = lsq[0] + lsq[1] + lsq[2] + lsq[3];
    float mean = s * (1.0f / CC);
    float var  = sq * (1.0f / CC) - mean * mean;
    float rstd = rsqrtf(var + 1e-5f);
    float4 gv = reinterpret_cast<const float4*>(g)[threadIdx.x];
    float4 bv = reinterpret_cast<const float4*>(bta)[threadIdx.x];
    float o0 = (v.x - mean) * rstd * gv.x + bv.x;
    float o1 = (v.y - mean) * rstd * gv.y + bv.y;
    float o2 = (v.z - mean) * rstd * gv.z + bv.z;
    float o3 = (v.w - mean) * rstd * gv.w + bv.w;
    uint2 p;
    p.x = (u32)f2bf(o0) | ((u32)f2bf(o1) << 16);
    p.y = (u32)f2bf(o2) | ((u32)f2bf(o3) << 16);
    reinterpret_cast<uint2*>(out + (size_t)row * CC)[threadIdx.x] = p;
}

// ---------------------------------------------------------------- bf16 MFMA GEMM
// out[M,N] = act(A[M,K] @ BT[N,K]^T + bias) (+res). 128x128 tile, BK=64, 4 waves.
__global__ __launch_bounds__(256) void gemm_bf16(const u16* __restrict__ A,
                                                 const u16* __restrict__ BT,
                                                 const float* __restrict__ bias,
                                                 const float* __restrict__ res,
                                                 float* __restrict__ outF,
                                                 u16* __restrict__ outB,
                                                 int N, int K, int act) {
    __shared__ u16 As[128 * 64];
    __shared__ u16 Bs[128 * 64];
    int tid = threadIdx.x;
    int wave = tid >> 6, lane = tid & 63;
    int wr = wave >> 1, wc = wave & 1;
    int row0 = blockIdx.y * 128, col0 = blockIdx.x * 128;
    f32x4 acc[4][4] = {};
    for (int kt = 0; kt < K; kt += 64) {
        #pragma unroll
        for (int i = 0; i < 4; ++i) {
            int s = tid + i * 256;        // 16B slot: row = s>>3, kblk = s&7
            int r = s >> 3, kb = s & 7;
            gload16(A + (size_t)(row0 + r) * K + kt + kb * 8, &As[s * 8]);
        }
        #pragma unroll
        for (int i = 0; i < 4; ++i) {
            int s = tid + i * 256;
            int r = s >> 3, kb = s & 7;
            gload16(BT + (size_t)(col0 + r) * K + kt + kb * 8, &Bs[s * 8]);
        }
        __syncthreads();
        #pragma unroll
        for (int ks = 0; ks < 2; ++ks) {
            s16x8 a[4], b[4];
            int lk = ks * 32 + (lane >> 4) * 8;
            int lr = lane & 15;
            #pragma unroll
            for (int i = 0; i < 4; ++i)
                a[i] = *reinterpret_cast<const s16x8*>(&As[(wr * 64 + i * 16 + lr) * 64 + lk]);
            #pragma unroll
            for (int j = 0; j < 4; ++j)
                b[j] = *reinterpret_cast<const s16x8*>(&Bs[(wc * 64 + j * 16 + lr) * 64 + lk]);
            #pragma unroll
            for (int i = 0; i < 4; ++i)
                #pragma unroll
                for (int j = 0; j < 4; ++j)
                    acc[i][j] = __builtin_amdgcn_mfma_f32_16x16x32_bf16(a[i], b[j], acc[i][j], 0, 0, 0);
        }
        __syncthreads();
    }
    int lr4 = (lane >> 4) * 4, lc = lane & 15;
    #pragma unroll
    for (int j = 0; j < 4; ++j) {
        int col = col0 + wc * 64 + j * 16 + lc;
        float bi = bias[col];
        #pragma unroll
        for (int i = 0; i < 4; ++i) {
            #pragma unroll
            for (int r = 0; r < 4; ++r) {
                int row = row0 + wr * 64 + i * 16 + lr4 + r;
                size_t o = (size_t)row * N + col;
                float v = acc[i][j][r] + bi;
                if (act) v = gelu_tanh(v);
                if (res) v += res[o];
                if (outF) outF[o] = v;
                else outB[o] = f2bf(v);
            }
        }
    }
}

// ------------------------------------------------- head pack with elu+1 (fp32 -> bf16)
__global__ __launch_bounds__(256) void pack_qk_kernel(const float* __restrict__ src, int rowstride,
                                                      int coloffbase, u16* __restrict__ dst) {
    int idx = blockIdx.x * 256 + threadIdx.x;  // 0 .. 2M-1 : [bh][t][d]
    int d = idx & 63;
    int t = (idx >> 6) & 1023;
    int h = (idx >> 16) & 15;
    int b = idx >> 20;
    float v = src[(size_t)(b * TT + t) * rowstride + coloffbase + h * HD + d];
    v = (v > 0.0f) ? v + 1.0f : expf(v);
    dst[idx] = f2bf(v);
}

// V pack transposed: src col (coloffbase+h*64+d) -> VT[bh][d][T] bf16
__global__ __launch_bounds__(256) void pack_vt_kernel(const float* __restrict__ src, int rowstride,
                                                      int coloffbase, u16* __restrict__ VT) {
    __shared__ float tl[64][65];
    int bh = blockIdx.y, b = bh >> 4, h = bh & 15;
    int t0 = blockIdx.x * 64;
    int c = threadIdx.x & 63, r4 = threadIdx.x >> 6;
    #pragma unroll
    for (int i = 0; i < 16; ++i) {
        int r = r4 * 16 + i;
        tl[r][c] = src[(size_t)(b * TT + t0 + r) * rowstride + coloffbase + h * HD + c];
    }
    __syncthreads();
    #pragma unroll
    for (int i = 0; i < 16; ++i) {
        int r = r4 * 16 + i;   // r = d, c = t_local
        VT[((size_t)bh * HD + r) * TT + t0 + c] = f2bf(tl[c][r]);
    }
}

// Ksum[bh][d] = sum_t Kf[bh][t][d]
__global__ __launch_bounds__(256) void ksum_kernel(const u16* __restrict__ Kf, float* __restrict__ Ksum) {
    int bh = blockIdx.x;
    int lane = threadIdx.x & 63;
    int w = threadIdx.x >> 6;
    const u16* base = Kf + (size_t)bh * TT * HD;
    float s = 0.f;
    for (int t = w; t < TT; t += 4) s += bf2f(base[t * HD + lane]);
    __shared__ float ls[4][64];
    ls[w][lane] = s;
    __syncthreads();
    if (threadIdx.x < 64)
        Ksum[bh * HD + lane] = ls[0][lane] + ls[1][lane] + ls[2][lane] + ls[3][lane];
}

// den[bh][t] = Qf[bh][t][:] . Ksum[bh][:]
__global__ __launch_bounds__(256) void denom_kernel(const u16* __restrict__ Qf,
                                                    const float* __restrict__ Ksum,
                                                    float* __restrict__ den) {
    int bh = blockIdx.x >> 8;
    int tblk = blockIdx.x & 255;
    int w = threadIdx.x >> 6, lane = threadIdx.x & 63;
    int t = tblk * 4 + w;
    float p = bf2f(Qf[((size_t)bh * TT + t) * HD + lane]) * Ksum[bh * HD + lane];
    #pragma unroll
    for (int off = 32; off >= 1; off >>= 1) p += __shfl_down(p, off);
    if (lane == 0) den[bh * TT + t] = p;
}

// In-place RoPE on bf16 [bh][T][64]
__global__ __launch_bounds__(256) void rope_kernel(u16* __restrict__ buf, const float* __restrict__ cosT,
                                                   const float* __restrict__ sinT) {
    int idx = blockIdx.x * 256 + threadIdx.x;  // 0 .. 1M-1
    int d = idx & 31;
    int t = (idx >> 5) & 1023;
    int bh = idx >> 15;
    float c = cosT[t * 32 + d], s = sinT[t * 32 + d];
    size_t base = ((size_t)bh * TT + t) * HD;
    float lo = bf2f(buf[base + d]), hi = bf2f(buf[base + d + 32]);
    buf[base + d]      = f2bf(lo * c - hi * s);
    buf[base + d + 32] = f2bf(hi * c + lo * s);
}

// ------------------------------------------------------- MFMA linear attention
// Qr,Kr [bh][T][64] bf16 (post-RoPE); VT [bh][64][T] bf16; den [bh][T] fp32
// out bf16 [B,T,C]: out[b][t][h*64+d] = (sum_s P[t][s] * V[s][d]) / den[t]
#define APAD 72   // row stride in elements (144 B, 16B-aligned, conflict-light)
__global__ __launch_bounds__(256) void attn_mfma(const u16* __restrict__ Qr,
                                                 const u16* __restrict__ Kr,
                                                 const u16* __restrict__ VT,
                                                 const float* __restrict__ den,
                                                 u16* __restrict__ out, int causal) {
    __shared__ u16 Qs[64 * APAD];
    __shared__ u16 Ks[64 * APAD];
    __shared__ u16 Vs[64 * APAD];   // [d][s]
    __shared__ u16 Ps[64 * APAD];
    int bh = blockIdx.y, b = bh >> 4, h = bh & 15;
    int t0 = blockIdx.x * 64;
    int tid = threadIdx.x, wave = tid >> 6, lane = tid & 63;
    // stage Q tile
    #pragma unroll
    for (int i = 0; i < 2; ++i) {
        int s = tid + i * 256;          // 512 slots of 16B
        int r = s >> 3, kb = s & 7;
        *reinterpret_cast<s16x8*>(&Qs[r * APAD + kb * 8]) =
            *reinterpret_cast<const s16x8*>(&Qr[((size_t)bh * TT + t0 + r) * HD + kb * 8]);
    }
    __syncthreads();
    int lr = lane & 15, lk = (lane >> 4) * 8;
    s16x8 qf0 = *reinterpret_cast<const s16x8*>(&Qs[(wave * 16 + lr) * APAD + lk]);
    s16x8 qf1 = *reinterpret_cast<const s16x8*>(&Qs[(wave * 16 + lr) * APAD + 32 + lk]);
    f32x4 accO[4] = {};
    int ntiles = causal ? (blockIdx.x + 1) : (TT / 64);
    for (int st = 0; st < ntiles; ++st) {
        int s0 = st * 64;
        __syncthreads();  // previous PV readers done before restage
        #pragma unroll
        for (int i = 0; i < 2; ++i) {
            int s = tid + i * 256;
            int r = s >> 3, kb = s & 7;
            *reinterpret_cast<s16x8*>(&Ks[r * APAD + kb * 8]) =
                *reinterpret_cast<const s16x8*>(&Kr[((size_t)bh * TT + s0 + r) * HD + kb * 8]);
            *reinterpret_cast<s16x8*>(&Vs[r * APAD + kb * 8]) =
                *reinterpret_cast<const s16x8*>(&VT[((size_t)bh * HD + r) * TT + s0 + kb * 8]);
        }
        __syncthreads();
        // S = Q . K^T  (per wave: 16 t-rows x 64 s-cols)
        f32x4 accS[4] = {};
        #pragma unroll
        for (int j = 0; j < 4; ++j) {
            s16x8 kb0 = *reinterpret_cast<const s16x8*>(&Ks[(j * 16 + lr) * APAD + lk]);
            s16x8 kb1 = *reinterpret_cast<const s16x8*>(&Ks[(j * 16 + lr) * APAD + 32 + lk]);
            accS[j] = __builtin_amdgcn_mfma_f32_16x16x32_bf16(qf0, kb0, accS[j], 0, 0, 0);
            accS[j] = __builtin_amdgcn_mfma_f32_16x16x32_bf16(qf1, kb1, accS[j], 0, 0, 0);
        }
        // mask + write P (bf16)
        int tl = wave * 16 + (lane >> 4) * 4;
        #pragma unroll
        for (int j = 0; j < 4; ++j) {
            #pragma unroll
            for (int r = 0; r < 4; ++r) {
                float v = accS[j][r];
                if (causal && (s0 + j * 16 + lr > t0 + tl + r)) v = 0.f;
                Ps[(tl + r) * APAD + j * 16 + lr] = f2bf(v);
            }
        }
        __syncthreads();
        // O += P . V   (A = P[t][s], B = V[s][d] read from Vs[d][s])
        #pragma unroll
        for (int ks = 0; ks < 2; ++ks) {
            s16x8 pa = *reinterpret_cast<const s16x8*>(&Ps[(wave * 16 + lr) * APAD + ks * 32 + lk]);
            #pragma unroll
            for (int j = 0; j < 4; ++j) {
                s16x8 vb = *reinterpret_cast<const s16x8*>(&Vs[(j * 16 + lr) * APAD + ks * 32 + lk]);
                accO[j] = __builtin_amdgcn_mfma_f32_16x16x32_bf16(pa, vb, accO[j], 0, 0, 0);
            }
        }
    }
    int tl = wave * 16 + (lane >> 4) * 4;
    float invd[4];
    #pragma unroll
    for (int r = 0; r < 4; ++r) invd[r] = 1.0f / den[bh * TT + t0 + tl + r];
    #pragma unroll
    for (int j = 0; j < 4; ++j)
        #pragma unroll
        for (int r = 0; r < 4; ++r)
            out[(size_t)(b * TT + t0 + tl + r) * CC + h * HD + j * 16 + lr] = f2bf(accO[j][r] * invd[r]);
}

// ---------------------------------------------------------------- launch
extern "C" void kernel_launch(void* const* d_in, const int* in_sizes, int n_in,
                              void* d_out, int out_size, void* d_ws, size_t ws_size,
                              hipStream_t stream) {
    const float* x        = (const float*)d_in[0];
    const float* memory   = (const float*)d_in[1];
    const float* ln1_g    = (const float*)d_in[2];
    const float* ln1_b    = (const float*)d_in[3];
    const float* sa_qkv_w = (const float*)d_in[4];
    const float* sa_qkv_b = (const float*)d_in[5];
    const float* sa_pr_w  = (const float*)d_in[6];
    const float* sa_pr_b  = (const float*)d_in[7];
    const float* ln2_g    = (const float*)d_in[8];
    const float* ln2_b    = (const float*)d_in[9];
    const float* ca_q_w   = (const float*)d_in[10];
    const float* ca_q_b   = (const float*)d_in[11];
    const float* ca_kv_w  = (const float*)d_in[12];
    const float* ca_kv_b  = (const float*)d_in[13];
    const float* ca_pr_w  = (const float*)d_in[14];
    const float* ca_pr_b  = (const float*)d_in[15];
    const float* ln3_g    = (const float*)d_in[16];
    const float* ln3_b    = (const float*)d_in[17];
    const float* fc_w     = (const float*)d_in[18];
    const float* fc_b     = (const float*)d_in[19];
    const float* fcp_w    = (const float*)d_in[20];
    const float* fcp_b    = (const float*)d_in[21];
    float* out = (float*)d_out;
    char* wsb  = (char*)d_ws;

    const size_t MB = 1024 * 1024;
    float* bigF   = (float*)wsb;                    // 6M floats (24 MB), later aliased by fcB
    float* bigF2  = bigF + 2 * MB;                  // kv fp32 (4M floats)
    u16*  qkvT  = (u16*)(wsb + 24 * MB);            // 3M el
    u16*  prT   = qkvT + 3 * MB;
    u16*  caqT  = prT + 1 * MB;
    u16*  cakvT = caqT + 1 * MB;
    u16*  caprT = cakvT + 2 * MB;
    u16*  fcT   = caprT + 1 * MB;
    u16*  fcpT  = fcT + 4 * MB;                     // ends at 24MB + 32MB
    u16*  memB  = (u16*)(wsb + 56 * MB);
    u16*  hB    = (u16*)(wsb + 60 * MB);
    u16*  h2B   = (u16*)(wsb + 64 * MB);
    u16*  Qb    = (u16*)(wsb + 68 * MB);
    u16*  Kb    = (u16*)(wsb + 72 * MB);
    u16*  VTb   = (u16*)(wsb + 76 * MB);
    float* Ksum = (float*)(wsb + 80 * MB);
    float* den  = Ksum + 2048;
    float* cosT = den + 32768;
    float* sinT = cosT + 32768;
    u16*  fcB   = (u16*)bigF;                       // alias: 8M el (16 MB)

    dim3 b256(256);

    // prep: tables, weight transposes, memory bf16
    rope_table_kernel<<<dim3(TT), dim3(32), 0, stream>>>(cosT, sinT);
    wtrans_kernel<<<dim3(48, 16), b256, 0, stream>>>(sa_qkv_w, qkvT, 1024, 3072);
    wtrans_kernel<<<dim3(16, 16), b256, 0, stream>>>(sa_pr_w, prT, 1024, 1024);
    wtrans_kernel<<<dim3(16, 16), b256, 0, stream>>>(ca_q_w, caqT, 1024, 1024);
    wtrans_kernel<<<dim3(32, 16), b256, 0, stream>>>(ca_kv_w, cakvT, 1024, 2048);
    wtrans_kernel<<<dim3(16, 16), b256, 0, stream>>>(ca_pr_w, caprT, 1024, 1024);
    wtrans_kernel<<<dim3(64, 16), b256, 0, stream>>>(fc_w, fcT, 1024, 4096);
    wtrans_kernel<<<dim3(16, 64), b256, 0, stream>>>(fcp_w, fcpT, 4096, 1024);
    f2b_kernel<<<dim3(2048), b256, 0, stream>>>(memory, memB);

    // ---- causal self-attention ----
    ln_kernel<<<dim3(MM), b256, 0, stream>>>(x, ln1_g, ln1_b, hB);
    gemm_bf16<<<dim3(24, 16), b256, 0, stream>>>(hB, qkvT, sa_qkv_b, nullptr, bigF, nullptr, 3072, 1024, 0);
    pack_qk_kernel<<<dim3(8192), b256, 0, stream>>>(bigF, 3072, 0,    Qb);
    pack_qk_kernel<<<dim3(8192), b256, 0, stream>>>(bigF, 3072, 1024, Kb);
    pack_vt_kernel<<<dim3(16, 32), b256, 0, stream>>>(bigF, 3072, 2048, VTb);
    ksum_kernel<<<dim3(32), b256, 0, stream>>>(Kb, Ksum);
    denom_kernel<<<dim3(8192), b256, 0, stream>>>(Qb, Ksum, den);
    rope_kernel<<<dim3(4096), b256, 0, stream>>>(Qb, cosT, sinT);
    rope_kernel<<<dim3(4096), b256, 0, stream>>>(Kb, cosT, sinT);
    attn_mfma<<<dim3(16, 32), b256, 0, stream>>>(Qb, Kb, VTb, den, h2B, 1);
    gemm_bf16<<<dim3(8, 16), b256, 0, stream>>>(h2B, prT, sa_pr_b, x, out, nullptr, 1024, 1024, 0);

    // ---- cross-attention ----
    ln_kernel<<<dim3(MM), b256, 0, stream>>>(out, ln2_g, ln2_b, hB);
    gemm_bf16<<<dim3(8, 16), b256, 0, stream>>>(hB, caqT, ca_q_b, nullptr, bigF, nullptr, 1024, 1024, 0);
    gemm_bf16<<<dim3(16, 16), b256, 0, stream>>>(memB, cakvT, ca_kv_b, nullptr, bigF2, nullptr, 2048, 1024, 0);
    pack_qk_kernel<<<dim3(8192), b256, 0, stream>>>(bigF, 1024, 0, Qb);
    pack_qk_kernel<<<dim3(8192), b256, 0, stream>>>(bigF2, 2048, 0,    Kb);
    pack_vt_kernel<<<dim3(16, 32), b256, 0, stream>>>(bigF2, 2048, 1024, VTb);
    ksum_kernel<<<dim3(32), b256, 0, stream>>>(Kb, Ksum);
    denom_kernel<<<dim3(8192), b256, 0, stream>>>(Qb, Ksum, den);
    rope_kernel<<<dim3(4096), b256, 0, stream>>>(Qb, cosT, sinT);
    rope_kernel<<<dim3(4096), b256, 0, stream>>>(Kb, cosT, sinT);
    attn_mfma<<<dim3(16, 32), b256, 0, stream>>>(Qb, Kb, VTb, den, h2B, 0);
    gemm_bf16<<<dim3(8, 16), b256, 0, stream>>>(h2B, caprT, ca_pr_b, out, out, nullptr, 1024, 1024, 0);

    // ---- MLP ----
    ln_kernel<<<dim3(MM), b256, 0, stream>>>(out, ln3_g, ln3_b, hB);
    gemm_bf16<<<dim3(32, 16), b256, 0, stream>>>(hB, fcT, fc_b, nullptr, nullptr, fcB, 4096, 1024, 1);
    gemm_bf16<<<dim3(8, 16), b256, 0, stream>>>(fcB, fcpT, fcp_b, out, out, nullptr, 1024, 4096, 0);
}

// Round 3
// 446.900 us; speedup vs baseline: 4.2702x; 1.2719x over previous
//
#include <hip/hip_runtime.h>
#include <math.h>

#define BB 2
#define TT 1024
#define CC 1024
#define HH 16
#define HD 64
#define MM (BB*TT)   // 2048 rows

typedef unsigned short u16;
typedef unsigned int u32;
typedef short s16x8 __attribute__((ext_vector_type(8)));
typedef float f32x4 __attribute__((ext_vector_type(4)));

__device__ __forceinline__ u16 f2bf(float f) {
    u32 u = __builtin_bit_cast(u32, f);
    u += 0x7fffu + ((u >> 16) & 1u);
    return (u16)(u >> 16);
}
__device__ __forceinline__ float bf2f(u16 h) {
    return __builtin_bit_cast(float, ((u32)h) << 16);
}
__device__ __forceinline__ void gload16(const void* g, void* l) {
    __builtin_amdgcn_global_load_lds((const __attribute__((address_space(1))) u32*)g,
                                     (__attribute__((address_space(3))) u32*)l, 16, 0, 0);
}
__device__ __forceinline__ float gelu_tanh(float x) {
    float x3 = x * x * x;
    return 0.5f * x * (1.0f + tanhf(0.7978845608028654f * (x + 0.044715f * x3)));
}
__device__ __forceinline__ float elu1(float v) {
    return (v > 0.0f) ? v + 1.0f : expf(v);
}

// ---------------------------------------------------------------- RoPE tables
__global__ void rope_table_kernel(float* __restrict__ cosT, float* __restrict__ sinT) {
    int t = blockIdx.x;
    int d = threadIdx.x;  // 0..31
    double inv = pow(10000.0, -((double)d) / 32.0);
    double ang = (double)t * inv;
    cosT[t * 32 + d] = (float)cos(ang);
    sinT[t * 32 + d] = (float)sin(ang);
}

// ------------------------------------------------- weight transpose fp32->bf16
// in [K][N] -> out [N][K] bf16
__global__ __launch_bounds__(256) void wtrans_kernel(const float* __restrict__ in,
                                                     u16* __restrict__ out, int K, int N) {
    __shared__ float tl[64][65];
    int n0 = blockIdx.x * 64, k0 = blockIdx.y * 64;
    int c = threadIdx.x & 63, r4 = threadIdx.x >> 6;
    #pragma unroll
    for (int i = 0; i < 16; ++i) {
        int r = r4 * 16 + i;
        tl[r][c] = in[(size_t)(k0 + r) * N + n0 + c];
    }
    __syncthreads();
    #pragma unroll
    for (int i = 0; i < 16; ++i) {
        int r = r4 * 16 + i;
        out[(size_t)(n0 + r) * K + k0 + c] = f2bf(tl[c][r]);
    }
}

// fp32 -> bf16 elementwise
__global__ __launch_bounds__(256) void f2b_kernel(const float* __restrict__ in, u16* __restrict__ out) {
    int i = blockIdx.x * 256 + threadIdx.x;
    float4 v = reinterpret_cast<const float4*>(in)[i];
    uint2 p;
    p.x = (u32)f2bf(v.x) | ((u32)f2bf(v.y) << 16);
    p.y = (u32)f2bf(v.z) | ((u32)f2bf(v.w) << 16);
    reinterpret_cast<uint2*>(out)[i] = p;
}

// ---------------------------------------------------------------- LayerNorm (fp32 in, bf16 out)
__global__ __launch_bounds__(256) void ln_kernel(const float* __restrict__ x,
                                                 const float* __restrict__ g,
                                                 const float* __restrict__ bta,
                                                 u16* __restrict__ out) {
    int row = blockIdx.x;
    const float* xr = x + (size_t)row * CC;
    float4 v = reinterpret_cast<const float4*>(xr)[threadIdx.x];
    float s  = v.x + v.y + v.z + v.w;
    float sq = v.x*v.x + v.y*v.y + v.z*v.z + v.w*v.w;
    #pragma unroll
    for (int off = 32; off >= 1; off >>= 1) {
        s  += __shfl_down(s, off);
        sq += __shfl_down(sq, off);
    }
    __shared__ float ls[4], lsq[4];
    int wave = threadIdx.x >> 6, lane = threadIdx.x & 63;
    if (lane == 0) { ls[wave] = s; lsq[wave] = sq; }
    __syncthreads();
    s  = ls[0] + ls[1] + ls[2] + ls[3];
    sq = lsq[0] + lsq[1] + lsq[2] + lsq[3];
    float mean = s * (1.0f / CC);
    float var  = sq * (1.0f / CC) - mean * mean;
    float rstd = rsqrtf(var + 1e-5f);
    float4 gv = reinterpret_cast<const float4*>(g)[threadIdx.x];
    float4 bv = reinterpret_cast<const float4*>(bta)[threadIdx.x];
    float o0 = (v.x - mean) * rstd * gv.x + bv.x;
    float o1 = (v.y - mean) * rstd * gv.y + bv.y;
    float o2 = (v.z - mean) * rstd * gv.z + bv.z;
    float o3 = (v.w - mean) * rstd * gv.w + bv.w;
    uint2 p;
    p.x = (u32)f2bf(o0) | ((u32)f2bf(o1) << 16);
    p.y = (u32)f2bf(o2) | ((u32)f2bf(o3) << 16);
    reinterpret_cast<uint2*>(out + (size_t)row * CC)[threadIdx.x] = p;
}

// ---------------------------------------------------------------- bf16 MFMA GEMM
// Epilogue modes
#define M_F32RES 0   // oF[row*N+col] = v + res[row*N+col]
#define M_GELU   1   // o1(bf16)[row*N+col] = gelu(v)
#define M_QKV    2   // col<1024: Q elu-pack -> o1 ; <2048: K elu-pack -> o2 ; else V -> o3 (VT layout)
#define M_Q      3   // all cols: Q elu-pack -> o1
#define M_KV     4   // col<1024: K elu-pack -> o1 ; else V -> o3

template <int MODE>
__device__ __forceinline__ void emit(int row, int col, float v,
                                     const float* __restrict__ res,
                                     float* __restrict__ oF, u16* __restrict__ o1,
                                     u16* __restrict__ o2, u16* __restrict__ o3, int N) {
    if constexpr (MODE == M_F32RES) {
        size_t o = (size_t)row * N + col;
        oF[o] = v + res[o];
    } else if constexpr (MODE == M_GELU) {
        o1[(size_t)row * N + col] = f2bf(gelu_tanh(v));
    } else {
        int b = row >> 10, t = row & 1023;
        if constexpr (MODE == M_QKV) {
            if (col < 1024) {
                int h = col >> 6, d = col & 63;
                o1[(((size_t)(b * HH + h)) * TT + t) * HD + d] = f2bf(elu1(v));
            } else if (col < 2048) {
                int c = col - 1024, h = c >> 6, d = c & 63;
                o2[(((size_t)(b * HH + h)) * TT + t) * HD + d] = f2bf(elu1(v));
            } else {
                int c = col - 2048, h = c >> 6, d = c & 63;
                o3[(((size_t)(b * HH + h)) * HD + d) * TT + t] = f2bf(v);
            }
        } else if constexpr (MODE == M_Q) {
            int h = col >> 6, d = col & 63;
            o1[(((size_t)(b * HH + h)) * TT + t) * HD + d] = f2bf(elu1(v));
        } else {  // M_KV
            if (col < 1024) {
                int h = col >> 6, d = col & 63;
                o1[(((size_t)(b * HH + h)) * TT + t) * HD + d] = f2bf(elu1(v));
            } else {
                int c = col - 1024, h = c >> 6, d = c & 63;
                o3[(((size_t)(b * HH + h)) * HD + d) * TT + t] = f2bf(v);
            }
        }
    }
}

// out = A[M,K] @ BT[N,K]^T + bias, epilogue per MODE. 4 waves (2x2), BK=64.
template <int BM, int BN, int MODE>
__global__ __launch_bounds__(256) void gemm_bf16(const u16* __restrict__ A,
                                                 const u16* __restrict__ BT,
                                                 const float* __restrict__ bias,
                                                 const float* __restrict__ res,
                                                 float* __restrict__ oF,
                                                 u16* __restrict__ o1,
                                                 u16* __restrict__ o2,
                                                 u16* __restrict__ o3,
                                                 int N, int K) {
    constexpr int WM = BM / 2, WN = BN / 2;
    constexpr int FI = WM / 16, FJ = WN / 16;
    __shared__ u16 As[BM * 64];
    __shared__ u16 Bs[BN * 64];
    int tid = threadIdx.x;
    int wave = tid >> 6, lane = tid & 63;
    int wr = wave >> 1, wc = wave & 1;
    int row0 = blockIdx.y * BM, col0 = blockIdx.x * BN;
    f32x4 acc[FI][FJ] = {};
    int lr = lane & 15;
    for (int kt = 0; kt < K; kt += 64) {
        #pragma unroll
        for (int i = 0; i < BM / 32; ++i) {
            int s = tid + i * 256;        // 16B slot: row = s>>3, kblk = s&7
            int r = s >> 3, kb = s & 7;
            gload16(A + (size_t)(row0 + r) * K + kt + kb * 8, &As[s * 8]);
        }
        #pragma unroll
        for (int i = 0; i < BN / 32; ++i) {
            int s = tid + i * 256;
            int r = s >> 3, kb = s & 7;
            gload16(BT + (size_t)(col0 + r) * K + kt + kb * 8, &Bs[s * 8]);
        }
        __syncthreads();
        #pragma unroll
        for (int ks = 0; ks < 2; ++ks) {
            s16x8 a[FI], b[FJ];
            int lk = ks * 32 + (lane >> 4) * 8;
            #pragma unroll
            for (int i = 0; i < FI; ++i)
                a[i] = *reinterpret_cast<const s16x8*>(&As[(wr * WM + i * 16 + lr) * 64 + lk]);
            #pragma unroll
            for (int j = 0; j < FJ; ++j)
                b[j] = *reinterpret_cast<const s16x8*>(&Bs[(wc * WN + j * 16 + lr) * 64 + lk]);
            #pragma unroll
            for (int i = 0; i < FI; ++i)
                #pragma unroll
                for (int j = 0; j < FJ; ++j)
                    acc[i][j] = __builtin_amdgcn_mfma_f32_16x16x32_bf16(a[i], b[j], acc[i][j], 0, 0, 0);
        }
        __syncthreads();
    }
    int lr4 = (lane >> 4) * 4;
    #pragma unroll
    for (int j = 0; j < FJ; ++j) {
        int col = col0 + wc * WN + j * 16 + lr;
        float bi = bias[col];
        #pragma unroll
        for (int i = 0; i < FI; ++i) {
            #pragma unroll
            for (int r = 0; r < 4; ++r) {
                int row = row0 + wr * WM + i * 16 + lr4 + r;
                emit<MODE>(row, col, acc[i][j][r] + bi, res, oF, o1, o2, o3, N);
            }
        }
    }
}

// Ksum[bh][d] = sum_t Kf[bh][t][d]
__global__ __launch_bounds__(256) void ksum_kernel(const u16* __restrict__ Kf, float* __restrict__ Ksum) {
    int bh = blockIdx.x;
    int lane = threadIdx.x & 63;
    int w = threadIdx.x >> 6;
    const u16* base = Kf + (size_t)bh * TT * HD;
    float s = 0.f;
    for (int t = w; t < TT; t += 4) s += bf2f(base[t * HD + lane]);
    __shared__ float ls[4][64];
    ls[w][lane] = s;
    __syncthreads();
    if (threadIdx.x < 64)
        Ksum[bh * HD + lane] = ls[0][lane] + ls[1][lane] + ls[2][lane] + ls[3][lane];
}

// den[bh][t] = Qf[bh][t][:] . Ksum[bh][:]
__global__ __launch_bounds__(256) void denom_kernel(const u16* __restrict__ Qf,
                                                    const float* __restrict__ Ksum,
                                                    float* __restrict__ den) {
    int bh = blockIdx.x >> 8;
    int tblk = blockIdx.x & 255;
    int w = threadIdx.x >> 6, lane = threadIdx.x & 63;
    int t = tblk * 4 + w;
    float p = bf2f(Qf[((size_t)bh * TT + t) * HD + lane]) * Ksum[bh * HD + lane];
    #pragma unroll
    for (int off = 32; off >= 1; off >>= 1) p += __shfl_down(p, off);
    if (lane == 0) den[bh * TT + t] = p;
}

// In-place RoPE on bf16 [bh][T][64]
__global__ __launch_bounds__(256) void rope_kernel(u16* __restrict__ buf, const float* __restrict__ cosT,
                                                   const float* __restrict__ sinT) {
    int idx = blockIdx.x * 256 + threadIdx.x;  // 0 .. 1M-1
    int d = idx & 31;
    int t = (idx >> 5) & 1023;
    int bh = idx >> 15;
    float c = cosT[t * 32 + d], s = sinT[t * 32 + d];
    size_t base = ((size_t)bh * TT + t) * HD;
    float lo = bf2f(buf[base + d]), hi = bf2f(buf[base + d + 32]);
    buf[base + d]      = f2bf(lo * c - hi * s);
    buf[base + d + 32] = f2bf(hi * c + lo * s);
}

// ------------------------------------------------------- MFMA linear attention
#define APAD 72
__global__ __launch_bounds__(256) void attn_mfma(const u16* __restrict__ Qr,
                                                 const u16* __restrict__ Kr,
                                                 const u16* __restrict__ VT,
                                                 const float* __restrict__ den,
                                                 u16* __restrict__ out, int causal) {
    __shared__ u16 Qs[64 * APAD];
    __shared__ u16 Ks[64 * APAD];
    __shared__ u16 Vs[64 * APAD];   // [d][s]
    __shared__ u16 Ps[64 * APAD];
    int bh = blockIdx.y, b = bh >> 4, h = bh & 15;
    int t0 = blockIdx.x * 64;
    int tid = threadIdx.x, wave = tid >> 6, lane = tid & 63;
    #pragma unroll
    for (int i = 0; i < 2; ++i) {
        int s = tid + i * 256;
        int r = s >> 3, kb = s & 7;
        *reinterpret_cast<s16x8*>(&Qs[r * APAD + kb * 8]) =
            *reinterpret_cast<const s16x8*>(&Qr[((size_t)bh * TT + t0 + r) * HD + kb * 8]);
    }
    __syncthreads();
    int lr = lane & 15, lk = (lane >> 4) * 8;
    s16x8 qf0 = *reinterpret_cast<const s16x8*>(&Qs[(wave * 16 + lr) * APAD + lk]);
    s16x8 qf1 = *reinterpret_cast<const s16x8*>(&Qs[(wave * 16 + lr) * APAD + 32 + lk]);
    f32x4 accO[4] = {};
    int ntiles = causal ? (blockIdx.x + 1) : (TT / 64);
    for (int st = 0; st < ntiles; ++st) {
        int s0 = st * 64;
        __syncthreads();
        #pragma unroll
        for (int i = 0; i < 2; ++i) {
            int s = tid + i * 256;
            int r = s >> 3, kb = s & 7;
            *reinterpret_cast<s16x8*>(&Ks[r * APAD + kb * 8]) =
                *reinterpret_cast<const s16x8*>(&Kr[((size_t)bh * TT + s0 + r) * HD + kb * 8]);
            *reinterpret_cast<s16x8*>(&Vs[r * APAD + kb * 8]) =
                *reinterpret_cast<const s16x8*>(&VT[((size_t)bh * HD + r) * TT + s0 + kb * 8]);
        }
        __syncthreads();
        f32x4 accS[4] = {};
        #pragma unroll
        for (int j = 0; j < 4; ++j) {
            s16x8 kb0 = *reinterpret_cast<const s16x8*>(&Ks[(j * 16 + lr) * APAD + lk]);
            s16x8 kb1 = *reinterpret_cast<const s16x8*>(&Ks[(j * 16 + lr) * APAD + 32 + lk]);
            accS[j] = __builtin_amdgcn_mfma_f32_16x16x32_bf16(qf0, kb0, accS[j], 0, 0, 0);
            accS[j] = __builtin_amdgcn_mfma_f32_16x16x32_bf16(qf1, kb1, accS[j], 0, 0, 0);
        }
        int tl = wave * 16 + (lane >> 4) * 4;
        #pragma unroll
        for (int j = 0; j < 4; ++j) {
            #pragma unroll
            for (int r = 0; r < 4; ++r) {
                float v = accS[j][r];
                if (causal && (s0 + j * 16 + lr > t0 + tl + r)) v = 0.f;
                Ps[(tl + r) * APAD + j * 16 + lr] = f2bf(v);
            }
        }
        __syncthreads();
        #pragma unroll
        for (int ks = 0; ks < 2; ++ks) {
            s16x8 pa = *reinterpret_cast<const s16x8*>(&Ps[(wave * 16 + lr) * APAD + ks * 32 + lk]);
            #pragma unroll
            for (int j = 0; j < 4; ++j) {
                s16x8 vb = *reinterpret_cast<const s16x8*>(&Vs[(j * 16 + lr) * APAD + ks * 32 + lk]);
                accO[j] = __builtin_amdgcn_mfma_f32_16x16x32_bf16(pa, vb, accO[j], 0, 0, 0);
            }
        }
    }
    int tl = wave * 16 + (lane >> 4) * 4;
    float invd[4];
    #pragma unroll
    for (int r = 0; r < 4; ++r) invd[r] = 1.0f / den[bh * TT + t0 + tl + r];
    #pragma unroll
    for (int j = 0; j < 4; ++j)
        #pragma unroll
        for (int r = 0; r < 4; ++r)
            out[(size_t)(b * TT + t0 + tl + r) * CC + h * HD + j * 16 + lr] = f2bf(accO[j][r] * invd[r]);
}

// ---------------------------------------------------------------- launch
extern "C" void kernel_launch(void* const* d_in, const int* in_sizes, int n_in,
                              void* d_out, int out_size, void* d_ws, size_t ws_size,
                              hipStream_t stream) {
    const float* x        = (const float*)d_in[0];
    const float* memory   = (const float*)d_in[1];
    const float* ln1_g    = (const float*)d_in[2];
    const float* ln1_b    = (const float*)d_in[3];
    const float* sa_qkv_w = (const float*)d_in[4];
    const float* sa_qkv_b = (const float*)d_in[5];
    const float* sa_pr_w  = (const float*)d_in[6];
    const float* sa_pr_b  = (const float*)d_in[7];
    const float* ln2_g    = (const float*)d_in[8];
    const float* ln2_b    = (const float*)d_in[9];
    const float* ca_q_w   = (const float*)d_in[10];
    const float* ca_q_b   = (const float*)d_in[11];
    const float* ca_kv_w  = (const float*)d_in[12];
    const float* ca_kv_b  = (const float*)d_in[13];
    const float* ca_pr_w  = (const float*)d_in[14];
    const float* ca_pr_b  = (const float*)d_in[15];
    const float* ln3_g    = (const float*)d_in[16];
    const float* ln3_b    = (const float*)d_in[17];
    const float* fc_w     = (const float*)d_in[18];
    const float* fc_b     = (const float*)d_in[19];
    const float* fcp_w    = (const float*)d_in[20];
    const float* fcp_b    = (const float*)d_in[21];
    float* out = (float*)d_out;
    char* wsb  = (char*)d_ws;

    const size_t MB = 1024 * 1024;
    u16* qkvT  = (u16*)wsb;                  // 3M el (6 MB)
    u16* prT   = (u16*)(wsb + 6 * MB);       // 1M el
    u16* caqT  = (u16*)(wsb + 8 * MB);
    u16* cakvT = (u16*)(wsb + 10 * MB);      // 2M el
    u16* caprT = (u16*)(wsb + 14 * MB);
    u16* fcT   = (u16*)(wsb + 16 * MB);      // 4M el
    u16* fcpT  = (u16*)(wsb + 24 * MB);      // 4M el -> ends 32 MB
    u16* memB  = (u16*)(wsb + 32 * MB);
    u16* hB    = (u16*)(wsb + 36 * MB);
    u16* h2B   = (u16*)(wsb + 40 * MB);
    u16* Qb    = (u16*)(wsb + 44 * MB);
    u16* Kb    = (u16*)(wsb + 48 * MB);
    u16* VTb   = (u16*)(wsb + 52 * MB);
    u16* fcB   = (u16*)(wsb + 56 * MB);      // 8M el (16 MB) -> ends 72 MB
    float* Ksum = (float*)(wsb + 72 * MB);
    float* den  = Ksum + 2048;
    float* cosT = den + 32768;
    float* sinT = cosT + 32768;

    dim3 b256(256);

    // prep
    rope_table_kernel<<<dim3(TT), dim3(32), 0, stream>>>(cosT, sinT);
    wtrans_kernel<<<dim3(48, 16), b256, 0, stream>>>(sa_qkv_w, qkvT, 1024, 3072);
    wtrans_kernel<<<dim3(16, 16), b256, 0, stream>>>(sa_pr_w, prT, 1024, 1024);
    wtrans_kernel<<<dim3(16, 16), b256, 0, stream>>>(ca_q_w, caqT, 1024, 1024);
    wtrans_kernel<<<dim3(32, 16), b256, 0, stream>>>(ca_kv_w, cakvT, 1024, 2048);
    wtrans_kernel<<<dim3(16, 16), b256, 0, stream>>>(ca_pr_w, caprT, 1024, 1024);
    wtrans_kernel<<<dim3(64, 16), b256, 0, stream>>>(fc_w, fcT, 1024, 4096);
    wtrans_kernel<<<dim3(16, 64), b256, 0, stream>>>(fcp_w, fcpT, 4096, 1024);
    f2b_kernel<<<dim3(2048), b256, 0, stream>>>(memory, memB);

    // ---- causal self-attention ----
    ln_kernel<<<dim3(MM), b256, 0, stream>>>(x, ln1_g, ln1_b, hB);
    gemm_bf16<128, 64, M_QKV><<<dim3(48, 16), b256, 0, stream>>>(hB, qkvT, sa_qkv_b, nullptr, nullptr, Qb, Kb, VTb, 3072, 1024);
    ksum_kernel<<<dim3(32), b256, 0, stream>>>(Kb, Ksum);
    denom_kernel<<<dim3(8192), b256, 0, stream>>>(Qb, Ksum, den);
    rope_kernel<<<dim3(4096), b256, 0, stream>>>(Qb, cosT, sinT);
    rope_kernel<<<dim3(4096), b256, 0, stream>>>(Kb, cosT, sinT);
    attn_mfma<<<dim3(16, 32), b256, 0, stream>>>(Qb, Kb, VTb, den, h2B, 1);
    gemm_bf16<64, 64, M_F32RES><<<dim3(16, 32), b256, 0, stream>>>(h2B, prT, sa_pr_b, x, out, nullptr, nullptr, nullptr, 1024, 1024);

    // ---- cross-attention ----
    ln_kernel<<<dim3(MM), b256, 0, stream>>>(out, ln2_g, ln2_b, hB);
    gemm_bf16<64, 64, M_Q><<<dim3(16, 32), b256, 0, stream>>>(hB, caqT, ca_q_b, nullptr, nullptr, Qb, nullptr, nullptr, 1024, 1024);
    gemm_bf16<128, 64, M_KV><<<dim3(32, 16), b256, 0, stream>>>(memB, cakvT, ca_kv_b, nullptr, nullptr, Kb, nullptr, VTb, 2048, 1024);
    ksum_kernel<<<dim3(32), b256, 0, stream>>>(Kb, Ksum);
    denom_kernel<<<dim3(8192), b256, 0, stream>>>(Qb, Ksum, den);
    rope_kernel<<<dim3(4096), b256, 0, stream>>>(Qb, cosT, sinT);
    rope_kernel<<<dim3(4096), b256, 0, stream>>>(Kb, cosT, sinT);
    attn_mfma<<<dim3(16, 32), b256, 0, stream>>>(Qb, Kb, VTb, den, h2B, 0);
    gemm_bf16<64, 64, M_F32RES><<<dim3(16, 32), b256, 0, stream>>>(h2B, caprT, ca_pr_b, out, out, nullptr, nullptr, nullptr, 1024, 1024);

    // ---- MLP ----
    ln_kernel<<<dim3(MM), b256, 0, stream>>>(out, ln3_g, ln3_b, hB);
    gemm_bf16<128, 128, M_GELU><<<dim3(32, 16), b256, 0, stream>>>(hB, fcT, fc_b, nullptr, nullptr, fcB, nullptr, nullptr, 4096, 1024);
    gemm_bf16<64, 64, M_F32RES><<<dim3(16, 32), b256, 0, stream>>>(fcB, fcpT, fcp_b, out, out, nullptr, nullptr, nullptr, 1024, 4096);
}

// Round 4
// 422.822 us; speedup vs baseline: 4.5134x; 1.0569x over previous
//
#include <hip/hip_runtime.h>
#include <math.h>

#define BB 2
#define TT 1024
#define CC 1024
#define HH 16
#define HD 64
#define MM (BB*TT)   // 2048 rows

typedef unsigned short u16;
typedef unsigned int u32;
typedef short s16x8 __attribute__((ext_vector_type(8)));
typedef float f32x4 __attribute__((ext_vector_type(4)));

__device__ __forceinline__ u16 f2bf(float f) {
    u32 u = __builtin_bit_cast(u32, f);
    u += 0x7fffu + ((u >> 16) & 1u);
    return (u16)(u >> 16);
}
__device__ __forceinline__ float bf2f(u16 h) {
    return __builtin_bit_cast(float, ((u32)h) << 16);
}
__device__ __forceinline__ void gload16(const void* g, void* l) {
    __builtin_amdgcn_global_load_lds((const __attribute__((address_space(1))) u32*)g,
                                     (__attribute__((address_space(3))) u32*)l, 16, 0, 0);
}
__device__ __forceinline__ float gelu_tanh(float x) {
    float x3 = x * x * x;
    return 0.5f * x * (1.0f + tanhf(0.7978845608028654f * (x + 0.044715f * x3)));
}
__device__ __forceinline__ float elu1(float v) {
    return (v > 0.0f) ? v + 1.0f : expf(v);
}

// ---------------------------------------------------------------- RoPE tables
__global__ void rope_table_kernel(float* __restrict__ cosT, float* __restrict__ sinT) {
    int t = blockIdx.x;
    int d = threadIdx.x;  // 0..31
    double inv = pow(10000.0, -((double)d) / 32.0);
    double ang = (double)t * inv;
    cosT[t * 32 + d] = (float)cos(ang);
    sinT[t * 32 + d] = (float)sin(ang);
}

// ------------------------------------------------- weight transpose fp32->bf16
__global__ __launch_bounds__(256) void wtrans_kernel(const float* __restrict__ in,
                                                     u16* __restrict__ out, int K, int N) {
    __shared__ float tl[64][65];
    int n0 = blockIdx.x * 64, k0 = blockIdx.y * 64;
    int c = threadIdx.x & 63, r4 = threadIdx.x >> 6;
    #pragma unroll
    for (int i = 0; i < 16; ++i) {
        int r = r4 * 16 + i;
        tl[r][c] = in[(size_t)(k0 + r) * N + n0 + c];
    }
    __syncthreads();
    #pragma unroll
    for (int i = 0; i < 16; ++i) {
        int r = r4 * 16 + i;
        out[(size_t)(n0 + r) * K + k0 + c] = f2bf(tl[c][r]);
    }
}

__global__ __launch_bounds__(256) void f2b_kernel(const float* __restrict__ in, u16* __restrict__ out) {
    int i = blockIdx.x * 256 + threadIdx.x;
    float4 v = reinterpret_cast<const float4*>(in)[i];
    uint2 p;
    p.x = (u32)f2bf(v.x) | ((u32)f2bf(v.y) << 16);
    p.y = (u32)f2bf(v.z) | ((u32)f2bf(v.w) << 16);
    reinterpret_cast<uint2*>(out)[i] = p;
}

// ---------------------------------------------------------------- LayerNorm
__global__ __launch_bounds__(256) void ln_kernel(const float* __restrict__ x,
                                                 const float* __restrict__ g,
                                                 const float* __restrict__ bta,
                                                 u16* __restrict__ out) {
    int row = blockIdx.x;
    const float* xr = x + (size_t)row * CC;
    float4 v = reinterpret_cast<const float4*>(xr)[threadIdx.x];
    float s  = v.x + v.y + v.z + v.w;
    float sq = v.x*v.x + v.y*v.y + v.z*v.z + v.w*v.w;
    #pragma unroll
    for (int off = 32; off >= 1; off >>= 1) {
        s  += __shfl_down(s, off);
        sq += __shfl_down(sq, off);
    }
    __shared__ float ls[4], lsq[4];
    int wave = threadIdx.x >> 6, lane = threadIdx.x & 63;
    if (lane == 0) { ls[wave] = s; lsq[wave] = sq; }
    __syncthreads();
    s  = ls[0] + ls[1] + ls[2] + ls[3];
    sq = lsq[0] + lsq[1] + lsq[2] + lsq[3];
    float mean = s * (1.0f / CC);
    float var  = sq * (1.0f / CC) - mean * mean;
    float rstd = rsqrtf(var + 1e-5f);
    float4 gv = reinterpret_cast<const float4*>(g)[threadIdx.x];
    float4 bv = reinterpret_cast<const float4*>(bta)[threadIdx.x];
    float o0 = (v.x - mean) * rstd * gv.x + bv.x;
    float o1 = (v.y - mean) * rstd * gv.y + bv.y;
    float o2 = (v.z - mean) * rstd * gv.z + bv.z;
    float o3 = (v.w - mean) * rstd * gv.w + bv.w;
    uint2 p;
    p.x = (u32)f2bf(o0) | ((u32)f2bf(o1) << 16);
    p.y = (u32)f2bf(o2) | ((u32)f2bf(o3) << 16);
    reinterpret_cast<uint2*>(out + (size_t)row * CC)[threadIdx.x] = p;
}

// ---------------------------------------------------------------- bf16 MFMA GEMM
#define M_F32RES 0   // oF[row*N+col] = v + res[row*N+col]
#define M_GELU   1   // o1(bf16) = gelu(v)
#define M_QKV    2   // col<1024: Q elu-pack -> o1 ; <2048: K elu-pack -> o2 ; else V -> o3 (VT)
#define M_PART   5   // fp32 partials (split-K), no bias
#define M_CAQKV  6   // merged ca_q (+hB) / ca_kv (+memB) with M_QKV-style epilogue

template <int MODE>
__device__ __forceinline__ void emit(int row, int col, float v,
                                     const float* __restrict__ res,
                                     float* __restrict__ oF, u16* __restrict__ o1,
                                     u16* __restrict__ o2, u16* __restrict__ o3, int N) {
    if constexpr (MODE == M_F32RES) {
        size_t o = (size_t)row * N + col;
        oF[o] = v + res[o];
    } else if constexpr (MODE == M_GELU) {
        o1[(size_t)row * N + col] = f2bf(gelu_tanh(v));
    } else {  // M_QKV mapping
        int b = row >> 10, t = row & 1023;
        if (col < 1024) {
            int h = col >> 6, d = col & 63;
            o1[(((size_t)(b * HH + h)) * TT + t) * HD + d] = f2bf(elu1(v));
        } else if (col < 2048) {
            int c = col - 1024, h = c >> 6, d = c & 63;
            o2[(((size_t)(b * HH + h)) * TT + t) * HD + d] = f2bf(elu1(v));
        } else {
            int c = col - 2048, h = c >> 6, d = c & 63;
            o3[(((size_t)(b * HH + h)) * HD + d) * TT + t] = f2bf(v);
        }
    }
}

// out = A[M,K] @ BT[N,K]^T (+bias), epilogue per MODE. 4 waves (2x2), BK=64.
template <int BM, int BN, int MODE, int SPLITK>
__global__ __launch_bounds__(256) void gemm_bf16(const u16* __restrict__ A,
                                                 const u16* __restrict__ A2,
                                                 const u16* __restrict__ BT,
                                                 const u16* __restrict__ BT2,
                                                 const float* __restrict__ bias,
                                                 const float* __restrict__ bias2,
                                                 const float* __restrict__ res,
                                                 float* __restrict__ oF,
                                                 u16* __restrict__ o1,
                                                 u16* __restrict__ o2,
                                                 u16* __restrict__ o3,
                                                 int N, int K) {
    constexpr int WM = BM / 2, WN = BN / 2;
    constexpr int FI = WM / 16, FJ = WN / 16;
    __shared__ u16 As[BM * 64];
    __shared__ u16 Bs[BN * 64];
    int tid = threadIdx.x;
    int wave = tid >> 6, lane = tid & 63;
    int wr = wave >> 1, wc = wave & 1;
    int row0 = blockIdx.y * BM, col0 = blockIdx.x * BN;
    const u16* Ause = A;
    const u16* Buse = BT;
    const float* buse = bias;
    if constexpr (MODE == M_CAQKV) {
        if (col0 >= 1024) {
            Ause = A2;
            Buse = BT2 - (size_t)1024 * K;   // index with global col
            buse = bias2 - 1024;
        }
    }
    int kbeg = 0, kcnt = K;
    if constexpr (SPLITK > 1) { kcnt = K / SPLITK; kbeg = blockIdx.z * kcnt; }
    f32x4 acc[FI][FJ] = {};
    int lr = lane & 15;
    for (int kt = kbeg; kt < kbeg + kcnt; kt += 64) {
        #pragma unroll
        for (int i = 0; i < BM / 32; ++i) {
            int s = tid + i * 256;
            int r = s >> 3, kb = s & 7;
            gload16(Ause + (size_t)(row0 + r) * K + kt + kb * 8, &As[s * 8]);
        }
        #pragma unroll
        for (int i = 0; i < BN / 32; ++i) {
            int s = tid + i * 256;
            int r = s >> 3, kb = s & 7;
            gload16(Buse + (size_t)(col0 + r) * K + kt + kb * 8, &Bs[s * 8]);
        }
        __syncthreads();
        #pragma unroll
        for (int ks = 0; ks < 2; ++ks) {
            s16x8 a[FI], b[FJ];
            int lk = ks * 32 + (lane >> 4) * 8;
            #pragma unroll
            for (int i = 0; i < FI; ++i)
                a[i] = *reinterpret_cast<const s16x8*>(&As[(wr * WM + i * 16 + lr) * 64 + lk]);
            #pragma unroll
            for (int j = 0; j < FJ; ++j)
                b[j] = *reinterpret_cast<const s16x8*>(&Bs[(wc * WN + j * 16 + lr) * 64 + lk]);
            #pragma unroll
            for (int i = 0; i < FI; ++i)
                #pragma unroll
                for (int j = 0; j < FJ; ++j)
                    acc[i][j] = __builtin_amdgcn_mfma_f32_16x16x32_bf16(a[i], b[j], acc[i][j], 0, 0, 0);
        }
        __syncthreads();
    }
    int lr4 = (lane >> 4) * 4;
    if constexpr (MODE == M_PART) {
        size_t zoff = (size_t)blockIdx.z * (size_t)(gridDim.y * BM) * N;
        #pragma unroll
        for (int j = 0; j < FJ; ++j) {
            int col = col0 + wc * WN + j * 16 + lr;
            #pragma unroll
            for (int i = 0; i < FI; ++i)
                #pragma unroll
                for (int r = 0; r < 4; ++r) {
                    int row = row0 + wr * WM + i * 16 + lr4 + r;
                    oF[zoff + (size_t)row * N + col] = acc[i][j][r];
                }
        }
    } else {
        constexpr int EM = (MODE == M_CAQKV) ? M_QKV : MODE;
        #pragma unroll
        for (int j = 0; j < FJ; ++j) {
            int col = col0 + wc * WN + j * 16 + lr;
            float bi = buse[col];
            #pragma unroll
            for (int i = 0; i < FI; ++i)
                #pragma unroll
                for (int r = 0; r < 4; ++r) {
                    int row = row0 + wr * WM + i * 16 + lr4 + r;
                    emit<EM>(row, col, acc[i][j][r] + bi, res, oF, o1, o2, o3, N);
                }
        }
    }
}

// split-K reduce: out = sum_s P[s] + bias + res   (float4 over M*N)
template <int S>
__global__ __launch_bounds__(256) void reduce_res_kernel(const float* __restrict__ P,
                                                         const float* __restrict__ bias,
                                                         const float* __restrict__ res,
                                                         float* __restrict__ out,
                                                         int N, int total4) {
    int idx = blockIdx.x * 256 + threadIdx.x;
    if (idx >= total4) return;
    float4 b = reinterpret_cast<const float4*>(bias)[idx & (N / 4 - 1)];
    float4 r = reinterpret_cast<const float4*>(res)[idx];
    float4 a = {b.x + r.x, b.y + r.y, b.z + r.z, b.w + r.w};
    #pragma unroll
    for (int s = 0; s < S; ++s) {
        float4 p = reinterpret_cast<const float4*>(P)[(size_t)s * total4 + idx];
        a.x += p.x; a.y += p.y; a.z += p.z; a.w += p.w;
    }
    reinterpret_cast<float4*>(out)[idx] = a;
}

// Ksum[bh][d] = sum_t Kf[bh][t][d]
__global__ __launch_bounds__(256) void ksum_kernel(const u16* __restrict__ Kf, float* __restrict__ Ksum) {
    int bh = blockIdx.x;
    int lane = threadIdx.x & 63;
    int w = threadIdx.x >> 6;
    const u16* base = Kf + (size_t)bh * TT * HD;
    float s = 0.f;
    for (int t = w; t < TT; t += 4) s += bf2f(base[t * HD + lane]);
    __shared__ float ls[4][64];
    ls[w][lane] = s;
    __syncthreads();
    if (threadIdx.x < 64)
        Ksum[bh * HD + lane] = ls[0][lane] + ls[1][lane] + ls[2][lane] + ls[3][lane];
}

__global__ __launch_bounds__(256) void denom_kernel(const u16* __restrict__ Qf,
                                                    const float* __restrict__ Ksum,
                                                    float* __restrict__ den) {
    int bh = blockIdx.x >> 8;
    int tblk = blockIdx.x & 255;
    int w = threadIdx.x >> 6, lane = threadIdx.x & 63;
    int t = tblk * 4 + w;
    float p = bf2f(Qf[((size_t)bh * TT + t) * HD + lane]) * Ksum[bh * HD + lane];
    #pragma unroll
    for (int off = 32; off >= 1; off >>= 1) p += __shfl_down(p, off);
    if (lane == 0) den[bh * TT + t] = p;
}

__global__ __launch_bounds__(256) void rope_kernel(u16* __restrict__ buf, const float* __restrict__ cosT,
                                                   const float* __restrict__ sinT) {
    int idx = blockIdx.x * 256 + threadIdx.x;
    int d = idx & 31;
    int t = (idx >> 5) & 1023;
    int bh = idx >> 15;
    float c = cosT[t * 32 + d], s = sinT[t * 32 + d];
    size_t base = ((size_t)bh * TT + t) * HD;
    float lo = bf2f(buf[base + d]), hi = bf2f(buf[base + d + 32]);
    buf[base + d]      = f2bf(lo * c - hi * s);
    buf[base + d + 32] = f2bf(hi * c + lo * s);
}

// ------------------------------------------------------- MFMA linear attention
#define APAD 72
__global__ __launch_bounds__(256) void attn_mfma(const u16* __restrict__ Qr,
                                                 const u16* __restrict__ Kr,
                                                 const u16* __restrict__ VT,
                                                 const float* __restrict__ den,
                                                 u16* __restrict__ out, int causal) {
    __shared__ u16 Qs[64 * APAD];
    __shared__ u16 Ks[64 * APAD];
    __shared__ u16 Vs[64 * APAD];
    __shared__ u16 Ps[64 * APAD];
    int bh = blockIdx.y, b = bh >> 4, h = bh & 15;
    int t0 = blockIdx.x * 64;
    int tid = threadIdx.x, wave = tid >> 6, lane = tid & 63;
    #pragma unroll
    for (int i = 0; i < 2; ++i) {
        int s = tid + i * 256;
        int r = s >> 3, kb = s & 7;
        *reinterpret_cast<s16x8*>(&Qs[r * APAD + kb * 8]) =
            *reinterpret_cast<const s16x8*>(&Qr[((size_t)bh * TT + t0 + r) * HD + kb * 8]);
    }
    __syncthreads();
    int lr = lane & 15, lk = (lane >> 4) * 8;
    s16x8 qf0 = *reinterpret_cast<const s16x8*>(&Qs[(wave * 16 + lr) * APAD + lk]);
    s16x8 qf1 = *reinterpret_cast<const s16x8*>(&Qs[(wave * 16 + lr) * APAD + 32 + lk]);
    f32x4 accO[4] = {};
    int ntiles = causal ? (blockIdx.x + 1) : (TT / 64);
    for (int st = 0; st < ntiles; ++st) {
        int s0 = st * 64;
        __syncthreads();
        #pragma unroll
        for (int i = 0; i < 2; ++i) {
            int s = tid + i * 256;
            int r = s >> 3, kb = s & 7;
            *reinterpret_cast<s16x8*>(&Ks[r * APAD + kb * 8]) =
                *reinterpret_cast<const s16x8*>(&Kr[((size_t)bh * TT + s0 + r) * HD + kb * 8]);
            *reinterpret_cast<s16x8*>(&Vs[r * APAD + kb * 8]) =
                *reinterpret_cast<const s16x8*>(&VT[((size_t)bh * HD + r) * TT + s0 + kb * 8]);
        }
        __syncthreads();
        f32x4 accS[4] = {};
        #pragma unroll
        for (int j = 0; j < 4; ++j) {
            s16x8 kb0 = *reinterpret_cast<const s16x8*>(&Ks[(j * 16 + lr) * APAD + lk]);
            s16x8 kb1 = *reinterpret_cast<const s16x8*>(&Ks[(j * 16 + lr) * APAD + 32 + lk]);
            accS[j] = __builtin_amdgcn_mfma_f32_16x16x32_bf16(qf0, kb0, accS[j], 0, 0, 0);
            accS[j] = __builtin_amdgcn_mfma_f32_16x16x32_bf16(qf1, kb1, accS[j], 0, 0, 0);
        }
        int tl = wave * 16 + (lane >> 4) * 4;
        #pragma unroll
        for (int j = 0; j < 4; ++j) {
            #pragma unroll
            for (int r = 0; r < 4; ++r) {
                float v = accS[j][r];
                if (causal && (s0 + j * 16 + lr > t0 + tl + r)) v = 0.f;
                Ps[(tl + r) * APAD + j * 16 + lr] = f2bf(v);
            }
        }
        __syncthreads();
        #pragma unroll
        for (int ks = 0; ks < 2; ++ks) {
            s16x8 pa = *reinterpret_cast<const s16x8*>(&Ps[(wave * 16 + lr) * APAD + ks * 32 + lk]);
            #pragma unroll
            for (int j = 0; j < 4; ++j) {
                s16x8 vb = *reinterpret_cast<const s16x8*>(&Vs[(j * 16 + lr) * APAD + ks * 32 + lk]);
                accO[j] = __builtin_amdgcn_mfma_f32_16x16x32_bf16(pa, vb, accO[j], 0, 0, 0);
            }
        }
    }
    int tl = wave * 16 + (lane >> 4) * 4;
    float invd[4];
    #pragma unroll
    for (int r = 0; r < 4; ++r) invd[r] = 1.0f / den[bh * TT + t0 + tl + r];
    #pragma unroll
    for (int j = 0; j < 4; ++j)
        #pragma unroll
        for (int r = 0; r < 4; ++r)
            out[(size_t)(b * TT + t0 + tl + r) * CC + h * HD + j * 16 + lr] = f2bf(accO[j][r] * invd[r]);
}

// ---------------------------------------------------------------- launch
extern "C" void kernel_launch(void* const* d_in, const int* in_sizes, int n_in,
                              void* d_out, int out_size, void* d_ws, size_t ws_size,
                              hipStream_t stream) {
    const float* x        = (const float*)d_in[0];
    const float* memory   = (const float*)d_in[1];
    const float* ln1_g    = (const float*)d_in[2];
    const float* ln1_b    = (const float*)d_in[3];
    const float* sa_qkv_w = (const float*)d_in[4];
    const float* sa_qkv_b = (const float*)d_in[5];
    const float* sa_pr_w  = (const float*)d_in[6];
    const float* sa_pr_b  = (const float*)d_in[7];
    const float* ln2_g    = (const float*)d_in[8];
    const float* ln2_b    = (const float*)d_in[9];
    const float* ca_q_w   = (const float*)d_in[10];
    const float* ca_q_b   = (const float*)d_in[11];
    const float* ca_kv_w  = (const float*)d_in[12];
    const float* ca_kv_b  = (const float*)d_in[13];
    const float* ca_pr_w  = (const float*)d_in[14];
    const float* ca_pr_b  = (const float*)d_in[15];
    const float* ln3_g    = (const float*)d_in[16];
    const float* ln3_b    = (const float*)d_in[17];
    const float* fc_w     = (const float*)d_in[18];
    const float* fc_b     = (const float*)d_in[19];
    const float* fcp_w    = (const float*)d_in[20];
    const float* fcp_b    = (const float*)d_in[21];
    float* out = (float*)d_out;
    char* wsb  = (char*)d_ws;

    const size_t MB = 1024 * 1024;
    u16* qkvT  = (u16*)wsb;                  // 6 MB
    u16* prT   = (u16*)(wsb + 6 * MB);       // 2 MB
    u16* caqT  = (u16*)(wsb + 8 * MB);       // 2 MB
    u16* cakvT = (u16*)(wsb + 10 * MB);      // 4 MB
    u16* caprT = (u16*)(wsb + 14 * MB);      // 2 MB
    u16* fcT   = (u16*)(wsb + 16 * MB);      // 8 MB
    u16* fcpT  = (u16*)(wsb + 24 * MB);      // 8 MB
    u16* memB  = (u16*)(wsb + 32 * MB);      // 4 MB
    u16* hB    = (u16*)(wsb + 36 * MB);      // 4 MB
    u16* h2B   = (u16*)(wsb + 40 * MB);      // 4 MB
    u16* Qb    = (u16*)(wsb + 44 * MB);      // 4 MB
    u16* Kb    = (u16*)(wsb + 48 * MB);      // 4 MB
    u16* VTb   = (u16*)(wsb + 52 * MB);      // 4 MB
    // Pbuf (16 MB) aliases Qb/Kb/VTb + 4MB: only written AFTER attn consumed them
    float* Pbuf = (float*)(wsb + 44 * MB);   // 44..60 MB
    u16* fcB   = (u16*)(wsb + 60 * MB);      // 16 MB -> 76 MB
    float* Ksum = (float*)(wsb + 76 * MB);
    float* den  = Ksum + 2048;
    float* cosT = den + 32768;
    float* sinT = cosT + 32768;

    dim3 b256(256);
    const int TOT4 = MM * CC / 4;  // 524288

    // prep
    rope_table_kernel<<<dim3(TT), dim3(32), 0, stream>>>(cosT, sinT);
    wtrans_kernel<<<dim3(48, 16), b256, 0, stream>>>(sa_qkv_w, qkvT, 1024, 3072);
    wtrans_kernel<<<dim3(16, 16), b256, 0, stream>>>(sa_pr_w, prT, 1024, 1024);
    wtrans_kernel<<<dim3(16, 16), b256, 0, stream>>>(ca_q_w, caqT, 1024, 1024);
    wtrans_kernel<<<dim3(32, 16), b256, 0, stream>>>(ca_kv_w, cakvT, 1024, 2048);
    wtrans_kernel<<<dim3(16, 16), b256, 0, stream>>>(ca_pr_w, caprT, 1024, 1024);
    wtrans_kernel<<<dim3(64, 16), b256, 0, stream>>>(fc_w, fcT, 1024, 4096);
    wtrans_kernel<<<dim3(16, 64), b256, 0, stream>>>(fcp_w, fcpT, 4096, 1024);
    f2b_kernel<<<dim3(2048), b256, 0, stream>>>(memory, memB);

    // ---- causal self-attention ----
    ln_kernel<<<dim3(MM), b256, 0, stream>>>(x, ln1_g, ln1_b, hB);
    gemm_bf16<128, 64, M_QKV, 1><<<dim3(48, 16), b256, 0, stream>>>(
        hB, nullptr, qkvT, nullptr, sa_qkv_b, nullptr, nullptr,
        nullptr, Qb, Kb, VTb, 3072, 1024);
    ksum_kernel<<<dim3(32), b256, 0, stream>>>(Kb, Ksum);
    denom_kernel<<<dim3(8192), b256, 0, stream>>>(Qb, Ksum, den);
    rope_kernel<<<dim3(4096), b256, 0, stream>>>(Qb, cosT, sinT);
    rope_kernel<<<dim3(4096), b256, 0, stream>>>(Kb, cosT, sinT);
    attn_mfma<<<dim3(16, 32), b256, 0, stream>>>(Qb, Kb, VTb, den, h2B, 1);
    gemm_bf16<64, 64, M_PART, 2><<<dim3(16, 32, 2), b256, 0, stream>>>(
        h2B, nullptr, prT, nullptr, nullptr, nullptr, nullptr,
        Pbuf, nullptr, nullptr, nullptr, 1024, 1024);
    reduce_res_kernel<2><<<dim3(TOT4 / 256), b256, 0, stream>>>(Pbuf, sa_pr_b, x, out, 1024, TOT4);

    // ---- cross-attention ----
    ln_kernel<<<dim3(MM), b256, 0, stream>>>(out, ln2_g, ln2_b, hB);
    gemm_bf16<128, 64, M_CAQKV, 1><<<dim3(48, 16), b256, 0, stream>>>(
        hB, memB, caqT, cakvT, ca_q_b, ca_kv_b, nullptr,
        nullptr, Qb, Kb, VTb, 3072, 1024);
    ksum_kernel<<<dim3(32), b256, 0, stream>>>(Kb, Ksum);
    denom_kernel<<<dim3(8192), b256, 0, stream>>>(Qb, Ksum, den);
    rope_kernel<<<dim3(4096), b256, 0, stream>>>(Qb, cosT, sinT);
    rope_kernel<<<dim3(4096), b256, 0, stream>>>(Kb, cosT, sinT);
    attn_mfma<<<dim3(16, 32), b256, 0, stream>>>(Qb, Kb, VTb, den, h2B, 0);
    gemm_bf16<64, 64, M_PART, 2><<<dim3(16, 32, 2), b256, 0, stream>>>(
        h2B, nullptr, caprT, nullptr, nullptr, nullptr, nullptr,
        Pbuf, nullptr, nullptr, nullptr, 1024, 1024);
    reduce_res_kernel<2><<<dim3(TOT4 / 256), b256, 0, stream>>>(Pbuf, ca_pr_b, out, out, 1024, TOT4);

    // ---- MLP ----
    ln_kernel<<<dim3(MM), b256, 0, stream>>>(out, ln3_g, ln3_b, hB);
    gemm_bf16<128, 64, M_GELU, 1><<<dim3(64, 16), b256, 0, stream>>>(
        hB, nullptr, fcT, nullptr, fc_b, nullptr, nullptr,
        nullptr, fcB, nullptr, nullptr, 4096, 1024);
    gemm_bf16<64, 64, M_PART, 2><<<dim3(16, 32, 2), b256, 0, stream>>>(
        fcB, nullptr, fcpT, nullptr, nullptr, nullptr, nullptr,
        Pbuf, nullptr, nullptr, nullptr, 1024, 4096);
    reduce_res_kernel<2><<<dim3(TOT4 / 256), b256, 0, stream>>>(Pbuf, fcp_b, out, out, 1024, TOT4);
}

// Round 5
// 297.658 us; speedup vs baseline: 6.4113x; 1.4205x over previous
//
#include <hip/hip_runtime.h>
#include <math.h>

#define BB 2
#define TT 1024
#define CC 1024
#define HH 16
#define HD 64
#define MM (BB*TT)   // 2048 rows

typedef unsigned short u16;
typedef unsigned int u32;
typedef short s16x8 __attribute__((ext_vector_type(8)));
typedef float f32x4 __attribute__((ext_vector_type(4)));

__device__ __forceinline__ u16 f2bf(float f) {
    u32 u = __builtin_bit_cast(u32, f);
    u += 0x7fffu + ((u >> 16) & 1u);
    return (u16)(u >> 16);
}
__device__ __forceinline__ float bf2f(u16 h) {
    return __builtin_bit_cast(float, ((u32)h) << 16);
}
__device__ __forceinline__ void gload16(const void* g, void* l) {
    __builtin_amdgcn_global_load_lds((const __attribute__((address_space(1))) u32*)g,
                                     (__attribute__((address_space(3))) u32*)l, 16, 0, 0);
}
__device__ __forceinline__ float gelu_tanh(float x) {
    float x3 = x * x * x;
    return 0.5f * x * (1.0f + tanhf(0.7978845608028654f * (x + 0.044715f * x3)));
}
__device__ __forceinline__ float elu1(float v) {
    return (v > 0.0f) ? v + 1.0f : expf(v);
}

// ---------------------------------------------------------------- RoPE tables
__global__ void rope_table_kernel(float* __restrict__ cosT, float* __restrict__ sinT) {
    int t = blockIdx.x;
    int d = threadIdx.x;  // 0..31
    double inv = pow(10000.0, -((double)d) / 32.0);
    double ang = (double)t * inv;
    cosT[t * 32 + d] = (float)cos(ang);
    sinT[t * 32 + d] = (float)sin(ang);
}

// ------------------------------------------------- weight transpose fp32->bf16
__global__ __launch_bounds__(256) void wtrans_kernel(const float* __restrict__ in,
                                                     u16* __restrict__ out, int K, int N) {
    __shared__ float tl[64][65];
    int n0 = blockIdx.x * 64, k0 = blockIdx.y * 64;
    int c = threadIdx.x & 63, r4 = threadIdx.x >> 6;
    #pragma unroll
    for (int i = 0; i < 16; ++i) {
        int r = r4 * 16 + i;
        tl[r][c] = in[(size_t)(k0 + r) * N + n0 + c];
    }
    __syncthreads();
    #pragma unroll
    for (int i = 0; i < 16; ++i) {
        int r = r4 * 16 + i;
        out[(size_t)(n0 + r) * K + k0 + c] = f2bf(tl[c][r]);
    }
}

__global__ __launch_bounds__(256) void f2b_kernel(const float* __restrict__ in, u16* __restrict__ out) {
    int i = blockIdx.x * 256 + threadIdx.x;
    float4 v = reinterpret_cast<const float4*>(in)[i];
    uint2 p;
    p.x = (u32)f2bf(v.x) | ((u32)f2bf(v.y) << 16);
    p.y = (u32)f2bf(v.z) | ((u32)f2bf(v.w) << 16);
    reinterpret_cast<uint2*>(out)[i] = p;
}

// ---------------------------------------------------------------- LayerNorm
__global__ __launch_bounds__(256) void ln_kernel(const float* __restrict__ x,
                                                 const float* __restrict__ g,
                                                 const float* __restrict__ bta,
                                                 u16* __restrict__ out) {
    int row = blockIdx.x;
    const float* xr = x + (size_t)row * CC;
    float4 v = reinterpret_cast<const float4*>(xr)[threadIdx.x];
    float s  = v.x + v.y + v.z + v.w;
    float sq = v.x*v.x + v.y*v.y + v.z*v.z + v.w*v.w;
    #pragma unroll
    for (int off = 32; off >= 1; off >>= 1) {
        s  += __shfl_down(s, off);
        sq += __shfl_down(sq, off);
    }
    __shared__ float ls[4], lsq[4];
    int wave = threadIdx.x >> 6, lane = threadIdx.x & 63;
    if (lane == 0) { ls[wave] = s; lsq[wave] = sq; }
    __syncthreads();
    s  = ls[0] + ls[1] + ls[2] + ls[3];
    sq = lsq[0] + lsq[1] + lsq[2] + lsq[3];
    float mean = s * (1.0f / CC);
    float var  = sq * (1.0f / CC) - mean * mean;
    float rstd = rsqrtf(var + 1e-5f);
    float4 gv = reinterpret_cast<const float4*>(g)[threadIdx.x];
    float4 bv = reinterpret_cast<const float4*>(bta)[threadIdx.x];
    float o0 = (v.x - mean) * rstd * gv.x + bv.x;
    float o1 = (v.y - mean) * rstd * gv.y + bv.y;
    float o2 = (v.z - mean) * rstd * gv.z + bv.z;
    float o3 = (v.w - mean) * rstd * gv.w + bv.w;
    uint2 p;
    p.x = (u32)f2bf(o0) | ((u32)f2bf(o1) << 16);
    p.y = (u32)f2bf(o2) | ((u32)f2bf(o3) << 16);
    reinterpret_cast<uint2*>(out + (size_t)row * CC)[threadIdx.x] = p;
}

// ---------------------------------------------------------------- bf16 MFMA GEMM
#define M_F32RES 0   // oF = v + res
#define M_GELU   1   // o1(bf16) = gelu(v)
#define M_QKV    2   // col<1024: Q elu -> o1 ; <2048: K elu -> o2 (+KsumP) ; else V -> o3 (VT)
#define M_PART   5   // fp32 partials (split-K), no bias
#define M_CAQKV  6   // merged ca_q (+hB) / ca_kv (+memB), M_QKV-style epilogue

template <int MODE>
__device__ __forceinline__ void emit(int row, int col, float v,
                                     const float* __restrict__ res,
                                     float* __restrict__ oF, u16* __restrict__ o1,
                                     u16* __restrict__ o2, u16* __restrict__ o3, int N) {
    if constexpr (MODE == M_F32RES) {
        size_t o = (size_t)row * N + col;
        oF[o] = v + res[o];
    } else if constexpr (MODE == M_GELU) {
        o1[(size_t)row * N + col] = f2bf(gelu_tanh(v));
    } else {  // M_QKV mapping
        int b = row >> 10, t = row & 1023;
        if (col < 1024) {
            int h = col >> 6, d = col & 63;
            o1[(((size_t)(b * HH + h)) * TT + t) * HD + d] = f2bf(elu1(v));
        } else if (col < 2048) {
            int c = col - 1024, h = c >> 6, d = c & 63;
            o2[(((size_t)(b * HH + h)) * TT + t) * HD + d] = f2bf(elu1(v));
        } else {
            int c = col - 2048, h = c >> 6, d = c & 63;
            o3[(((size_t)(b * HH + h)) * HD + d) * TT + t] = f2bf(v);
        }
    }
}

// out = A[M,K] @ BT[N,K]^T (+bias), epilogue per MODE. 4 waves (2x2), BK=64.
// For M_QKV/M_CAQKV, K-column blocks additionally write per-rowblock column sums
// of elu1(K) to ksumP[blockIdx.y][col-1024] (deterministic, no atomics).
template <int BM, int BN, int MODE, int SPLITK>
__global__ __launch_bounds__(256) void gemm_bf16(const u16* __restrict__ A,
                                                 const u16* __restrict__ A2,
                                                 const u16* __restrict__ BT,
                                                 const u16* __restrict__ BT2,
                                                 const float* __restrict__ bias,
                                                 const float* __restrict__ bias2,
                                                 const float* __restrict__ res,
                                                 float* __restrict__ oF,
                                                 u16* __restrict__ o1,
                                                 u16* __restrict__ o2,
                                                 u16* __restrict__ o3,
                                                 float* __restrict__ ksumP,
                                                 int N, int K) {
    constexpr int WM = BM / 2, WN = BN / 2;
    constexpr int FI = WM / 16, FJ = WN / 16;
    __shared__ u16 As[BM * 64];
    __shared__ u16 Bs[BN * 64];
    int tid = threadIdx.x;
    int wave = tid >> 6, lane = tid & 63;
    int wr = wave >> 1, wc = wave & 1;
    int row0 = blockIdx.y * BM, col0 = blockIdx.x * BN;
    const u16* Ause = A;
    const u16* Buse = BT;
    const float* buse = bias;
    if constexpr (MODE == M_CAQKV) {
        if (col0 >= 1024) {
            Ause = A2;
            Buse = BT2 - (size_t)1024 * K;   // index with global col
            buse = bias2 - 1024;
        }
    }
    int kbeg = 0, kcnt = K;
    if constexpr (SPLITK > 1) { kcnt = K / SPLITK; kbeg = blockIdx.z * kcnt; }
    f32x4 acc[FI][FJ] = {};
    int lr = lane & 15;
    for (int kt = kbeg; kt < kbeg + kcnt; kt += 64) {
        #pragma unroll
        for (int i = 0; i < BM / 32; ++i) {
            int s = tid + i * 256;
            int r = s >> 3, kb = s & 7;
            gload16(Ause + (size_t)(row0 + r) * K + kt + kb * 8, &As[s * 8]);
        }
        #pragma unroll
        for (int i = 0; i < BN / 32; ++i) {
            int s = tid + i * 256;
            int r = s >> 3, kb = s & 7;
            gload16(Buse + (size_t)(col0 + r) * K + kt + kb * 8, &Bs[s * 8]);
        }
        __syncthreads();
        #pragma unroll
        for (int ks = 0; ks < 2; ++ks) {
            s16x8 a[FI], b[FJ];
            int lk = ks * 32 + (lane >> 4) * 8;
            #pragma unroll
            for (int i = 0; i < FI; ++i)
                a[i] = *reinterpret_cast<const s16x8*>(&As[(wr * WM + i * 16 + lr) * 64 + lk]);
            #pragma unroll
            for (int j = 0; j < FJ; ++j)
                b[j] = *reinterpret_cast<const s16x8*>(&Bs[(wc * WN + j * 16 + lr) * 64 + lk]);
            #pragma unroll
            for (int i = 0; i < FI; ++i)
                #pragma unroll
                for (int j = 0; j < FJ; ++j)
                    acc[i][j] = __builtin_amdgcn_mfma_f32_16x16x32_bf16(a[i], b[j], acc[i][j], 0, 0, 0);
        }
        __syncthreads();
    }
    int lr4 = (lane >> 4) * 4;
    if constexpr (MODE == M_PART) {
        size_t zoff = (size_t)blockIdx.z * (size_t)(gridDim.y * BM) * N;
        #pragma unroll
        for (int j = 0; j < FJ; ++j) {
            int col = col0 + wc * WN + j * 16 + lr;
            #pragma unroll
            for (int i = 0; i < FI; ++i)
                #pragma unroll
                for (int r = 0; r < 4; ++r) {
                    int row = row0 + wr * WM + i * 16 + lr4 + r;
                    oF[zoff + (size_t)row * N + col] = acc[i][j][r];
                }
        }
    } else {
        constexpr int EM = (MODE == M_CAQKV) ? M_QKV : MODE;
        #pragma unroll
        for (int j = 0; j < FJ; ++j) {
            int col = col0 + wc * WN + j * 16 + lr;
            float bi = buse[col];
            #pragma unroll
            for (int i = 0; i < FI; ++i)
                #pragma unroll
                for (int r = 0; r < 4; ++r) {
                    int row = row0 + wr * WM + i * 16 + lr4 + r;
                    emit<EM>(row, col, acc[i][j][r] + bi, res, oF, o1, o2, o3, N);
                }
        }
        // K-column sum partials (fused ksum)
        if constexpr (MODE == M_QKV || MODE == M_CAQKV) {
            if (col0 >= 1024 && col0 < 2048) {
                float* scratch = (float*)As;    // 64 cols * 8 contribs * 4B = 2 KB
                float part[FJ];
                #pragma unroll
                for (int j = 0; j < FJ; ++j) {
                    int col = col0 + wc * WN + j * 16 + lr;
                    float bi = buse[col];
                    float p = 0.f;
                    #pragma unroll
                    for (int i = 0; i < FI; ++i)
                        #pragma unroll
                        for (int r = 0; r < 4; ++r)
                            p += elu1(acc[i][j][r] + bi);
                    part[j] = p;
                }
                __syncthreads();
                int contrib = wr * 4 + (lane >> 4);
                #pragma unroll
                for (int j = 0; j < FJ; ++j) {
                    int colLocal = wc * WN + j * 16 + lr;
                    scratch[colLocal * 8 + contrib] = part[j];
                }
                __syncthreads();
                if (tid < BN) {
                    float s = 0.f;
                    #pragma unroll
                    for (int c = 0; c < 8; ++c) s += scratch[tid * 8 + c];
                    ksumP[(size_t)blockIdx.y * 1024 + (col0 - 1024) + tid] = s;
                }
            }
        }
    }
}

// Ksum[b*1024 + c] = sum_{rb<8} KsumP[b*8+rb][c]
__global__ __launch_bounds__(256) void ksum_fold_kernel(const float* __restrict__ KsumP,
                                                        float* __restrict__ Ksum) {
    int idx = blockIdx.x * 256 + threadIdx.x;   // 0..2047
    int b = idx >> 10, c = idx & 1023;
    float s = 0.f;
    #pragma unroll
    for (int rb = 0; rb < 8; ++rb) s += KsumP[(size_t)(b * 8 + rb) * 1024 + c];
    Ksum[idx] = s;
}

// split-K reduce: out = sum_s P[s] + bias + res
template <int S>
__global__ __launch_bounds__(256) void reduce_res_kernel(const float* __restrict__ P,
                                                         const float* __restrict__ bias,
                                                         const float* __restrict__ res,
                                                         float* __restrict__ out,
                                                         int N, int total4) {
    int idx = blockIdx.x * 256 + threadIdx.x;
    if (idx >= total4) return;
    float4 b = reinterpret_cast<const float4*>(bias)[idx & (N / 4 - 1)];
    float4 r = reinterpret_cast<const float4*>(res)[idx];
    float4 a = {b.x + r.x, b.y + r.y, b.z + r.z, b.w + r.w};
    #pragma unroll
    for (int s = 0; s < S; ++s) {
        float4 p = reinterpret_cast<const float4*>(P)[(size_t)s * total4 + idx];
        a.x += p.x; a.y += p.y; a.z += p.z; a.w += p.w;
    }
    reinterpret_cast<float4*>(out)[idx] = a;
}

// den[bh][t] = Qf[bh][t][:] . Ksum[bh][:]   (vectorized: 8 lanes/row, s16x8 loads)
__global__ __launch_bounds__(256) void denom_kernel(const u16* __restrict__ Qf,
                                                    const float* __restrict__ Ksum,
                                                    float* __restrict__ den) {
    int bh = blockIdx.x >> 5;            // 32 blocks per bh
    int t0 = (blockIdx.x & 31) * 32;     // 32 rows per block
    __shared__ float ks[64];
    if (threadIdx.x < 64) ks[threadIdx.x] = Ksum[bh * 64 + threadIdx.x];
    __syncthreads();
    int wave = threadIdx.x >> 6, lane = threadIdx.x & 63;
    int rw = lane >> 3, lsub = lane & 7;       // 8 rows/wave, 8 lanes/row
    int t = t0 + wave * 8 + rw;
    s16x8 q = *reinterpret_cast<const s16x8*>(&Qf[((size_t)bh * TT + t) * HD + lsub * 8]);
    float p = 0.f;
    #pragma unroll
    for (int e = 0; e < 8; ++e) p += bf2f((u16)q[e]) * ks[lsub * 8 + e];
    p += __shfl_xor(p, 1);
    p += __shfl_xor(p, 2);
    p += __shfl_xor(p, 4);
    if (lsub == 0) den[bh * TT + t] = p;
}

// In-place RoPE on bf16 [bh][T][64], 16B vector loads (4 threads/row)
__global__ __launch_bounds__(256) void rope_kernel(u16* __restrict__ buf, const float* __restrict__ cosT,
                                                   const float* __restrict__ sinT) {
    int g = blockIdx.x * 256 + threadIdx.x;    // 0 .. 131071
    int q = g & 3;
    int t = (g >> 2) & 1023;
    int bh = g >> 12;
    int d0 = q * 8;
    size_t base = ((size_t)bh * TT + t) * HD;
    s16x8 lo = *reinterpret_cast<const s16x8*>(&buf[base + d0]);
    s16x8 hi = *reinterpret_cast<const s16x8*>(&buf[base + 32 + d0]);
    const float4* cp = reinterpret_cast<const float4*>(&cosT[t * 32 + d0]);
    const float4* sp = reinterpret_cast<const float4*>(&sinT[t * 32 + d0]);
    float4 c0 = cp[0], c1 = cp[1], s0 = sp[0], s1 = sp[1];
    float cc[8] = {c0.x, c0.y, c0.z, c0.w, c1.x, c1.y, c1.z, c1.w};
    float ss[8] = {s0.x, s0.y, s0.z, s0.w, s1.x, s1.y, s1.z, s1.w};
    s16x8 nlo, nhi;
    #pragma unroll
    for (int e = 0; e < 8; ++e) {
        float l = bf2f((u16)lo[e]), h = bf2f((u16)hi[e]);
        nlo[e] = (short)f2bf(l * cc[e] - h * ss[e]);
        nhi[e] = (short)f2bf(h * cc[e] + l * ss[e]);
    }
    *reinterpret_cast<s16x8*>(&buf[base + d0]) = nlo;
    *reinterpret_cast<s16x8*>(&buf[base + 32 + d0]) = nhi;
}

// ------------------------------------------------------- MFMA linear attention
#define APAD 72
__global__ __launch_bounds__(256) void attn_mfma(const u16* __restrict__ Qr,
                                                 const u16* __restrict__ Kr,
                                                 const u16* __restrict__ VT,
                                                 const float* __restrict__ den,
                                                 u16* __restrict__ out, int causal) {
    __shared__ u16 Qs[64 * APAD];
    __shared__ u16 Ks[64 * APAD];
    __shared__ u16 Vs[64 * APAD];
    __shared__ u16 Ps[64 * APAD];
    int bh = blockIdx.y, b = bh >> 4, h = bh & 15;
    int t0 = blockIdx.x * 64;
    int tid = threadIdx.x, wave = tid >> 6, lane = tid & 63;
    #pragma unroll
    for (int i = 0; i < 2; ++i) {
        int s = tid + i * 256;
        int r = s >> 3, kb = s & 7;
        *reinterpret_cast<s16x8*>(&Qs[r * APAD + kb * 8]) =
            *reinterpret_cast<const s16x8*>(&Qr[((size_t)bh * TT + t0 + r) * HD + kb * 8]);
    }
    __syncthreads();
    int lr = lane & 15, lk = (lane >> 4) * 8;
    s16x8 qf0 = *reinterpret_cast<const s16x8*>(&Qs[(wave * 16 + lr) * APAD + lk]);
    s16x8 qf1 = *reinterpret_cast<const s16x8*>(&Qs[(wave * 16 + lr) * APAD + 32 + lk]);
    f32x4 accO[4] = {};
    int ntiles = causal ? (blockIdx.x + 1) : (TT / 64);
    for (int st = 0; st < ntiles; ++st) {
        int s0 = st * 64;
        __syncthreads();
        #pragma unroll
        for (int i = 0; i < 2; ++i) {
            int s = tid + i * 256;
            int r = s >> 3, kb = s & 7;
            *reinterpret_cast<s16x8*>(&Ks[r * APAD + kb * 8]) =
                *reinterpret_cast<const s16x8*>(&Kr[((size_t)bh * TT + s0 + r) * HD + kb * 8]);
            *reinterpret_cast<s16x8*>(&Vs[r * APAD + kb * 8]) =
                *reinterpret_cast<const s16x8*>(&VT[((size_t)bh * HD + r) * TT + s0 + kb * 8]);
        }
        __syncthreads();
        f32x4 accS[4] = {};
        #pragma unroll
        for (int j = 0; j < 4; ++j) {
            s16x8 kb0 = *reinterpret_cast<const s16x8*>(&Ks[(j * 16 + lr) * APAD + lk]);
            s16x8 kb1 = *reinterpret_cast<const s16x8*>(&Ks[(j * 16 + lr) * APAD + 32 + lk]);
            accS[j] = __builtin_amdgcn_mfma_f32_16x16x32_bf16(qf0, kb0, accS[j], 0, 0, 0);
            accS[j] = __builtin_amdgcn_mfma_f32_16x16x32_bf16(qf1, kb1, accS[j], 0, 0, 0);
        }
        int tl = wave * 16 + (lane >> 4) * 4;
        #pragma unroll
        for (int j = 0; j < 4; ++j) {
            #pragma unroll
            for (int r = 0; r < 4; ++r) {
                float v = accS[j][r];
                if (causal && (s0 + j * 16 + lr > t0 + tl + r)) v = 0.f;
                Ps[(tl + r) * APAD + j * 16 + lr] = f2bf(v);
            }
        }
        __syncthreads();
        #pragma unroll
        for (int ks = 0; ks < 2; ++ks) {
            s16x8 pa = *reinterpret_cast<const s16x8*>(&Ps[(wave * 16 + lr) * APAD + ks * 32 + lk]);
            #pragma unroll
            for (int j = 0; j < 4; ++j) {
                s16x8 vb = *reinterpret_cast<const s16x8*>(&Vs[(j * 16 + lr) * APAD + ks * 32 + lk]);
                accO[j] = __builtin_amdgcn_mfma_f32_16x16x32_bf16(pa, vb, accO[j], 0, 0, 0);
            }
        }
    }
    int tl = wave * 16 + (lane >> 4) * 4;
    float invd[4];
    #pragma unroll
    for (int r = 0; r < 4; ++r) invd[r] = 1.0f / den[bh * TT + t0 + tl + r];
    #pragma unroll
    for (int j = 0; j < 4; ++j)
        #pragma unroll
        for (int r = 0; r < 4; ++r)
            out[(size_t)(b * TT + t0 + tl + r) * CC + h * HD + j * 16 + lr] = f2bf(accO[j][r] * invd[r]);
}

// ---------------------------------------------------------------- launch
extern "C" void kernel_launch(void* const* d_in, const int* in_sizes, int n_in,
                              void* d_out, int out_size, void* d_ws, size_t ws_size,
                              hipStream_t stream) {
    const float* x        = (const float*)d_in[0];
    const float* memory   = (const float*)d_in[1];
    const float* ln1_g    = (const float*)d_in[2];
    const float* ln1_b    = (const float*)d_in[3];
    const float* sa_qkv_w = (const float*)d_in[4];
    const float* sa_qkv_b = (const float*)d_in[5];
    const float* sa_pr_w  = (const float*)d_in[6];
    const float* sa_pr_b  = (const float*)d_in[7];
    const float* ln2_g    = (const float*)d_in[8];
    const float* ln2_b    = (const float*)d_in[9];
    const float* ca_q_w   = (const float*)d_in[10];
    const float* ca_q_b   = (const float*)d_in[11];
    const float* ca_kv_w  = (const float*)d_in[12];
    const float* ca_kv_b  = (const float*)d_in[13];
    const float* ca_pr_w  = (const float*)d_in[14];
    const float* ca_pr_b  = (const float*)d_in[15];
    const float* ln3_g    = (const float*)d_in[16];
    const float* ln3_b    = (const float*)d_in[17];
    const float* fc_w     = (const float*)d_in[18];
    const float* fc_b     = (const float*)d_in[19];
    const float* fcp_w    = (const float*)d_in[20];
    const float* fcp_b    = (const float*)d_in[21];
    float* out = (float*)d_out;
    char* wsb  = (char*)d_ws;

    const size_t MB = 1024 * 1024;
    u16* qkvT  = (u16*)wsb;                  // 6 MB
    u16* prT   = (u16*)(wsb + 6 * MB);       // 2 MB
    u16* caqT  = (u16*)(wsb + 8 * MB);       // 2 MB
    u16* cakvT = (u16*)(wsb + 10 * MB);      // 4 MB
    u16* caprT = (u16*)(wsb + 14 * MB);      // 2 MB
    u16* fcT   = (u16*)(wsb + 16 * MB);      // 8 MB
    u16* fcpT  = (u16*)(wsb + 24 * MB);      // 8 MB
    u16* memB  = (u16*)(wsb + 32 * MB);      // 4 MB
    u16* hB    = (u16*)(wsb + 36 * MB);      // 4 MB
    u16* h2B   = (u16*)(wsb + 40 * MB);      // 4 MB
    u16* Qb    = (u16*)(wsb + 44 * MB);      // 4 MB
    u16* Kb    = (u16*)(wsb + 48 * MB);      // 4 MB
    u16* VTb   = (u16*)(wsb + 52 * MB);      // 4 MB
    float* Pbuf = (float*)(wsb + 44 * MB);   // 16 MB, aliases Q/K/VT after attn
    u16* fcB   = (u16*)(wsb + 60 * MB);      // 16 MB -> 76 MB
    float* Ksum  = (float*)(wsb + 76 * MB);            // 8 KB
    float* KsumP = (float*)(wsb + 76 * MB + 65536);    // 64 KB
    float* den   = (float*)(wsb + 76 * MB + 131072);   // 128 KB
    float* cosT  = (float*)(wsb + 76 * MB + 262144);   // 128 KB
    float* sinT  = (float*)(wsb + 76 * MB + 393216);   // 128 KB

    dim3 b256(256);
    const int TOT4 = MM * CC / 4;  // 524288

    // prep
    rope_table_kernel<<<dim3(TT), dim3(32), 0, stream>>>(cosT, sinT);
    wtrans_kernel<<<dim3(48, 16), b256, 0, stream>>>(sa_qkv_w, qkvT, 1024, 3072);
    wtrans_kernel<<<dim3(16, 16), b256, 0, stream>>>(sa_pr_w, prT, 1024, 1024);
    wtrans_kernel<<<dim3(16, 16), b256, 0, stream>>>(ca_q_w, caqT, 1024, 1024);
    wtrans_kernel<<<dim3(32, 16), b256, 0, stream>>>(ca_kv_w, cakvT, 1024, 2048);
    wtrans_kernel<<<dim3(16, 16), b256, 0, stream>>>(ca_pr_w, caprT, 1024, 1024);
    wtrans_kernel<<<dim3(64, 16), b256, 0, stream>>>(fc_w, fcT, 1024, 4096);
    wtrans_kernel<<<dim3(16, 64), b256, 0, stream>>>(fcp_w, fcpT, 4096, 1024);
    f2b_kernel<<<dim3(2048), b256, 0, stream>>>(memory, memB);

    // ---- causal self-attention ----
    ln_kernel<<<dim3(MM), b256, 0, stream>>>(x, ln1_g, ln1_b, hB);
    gemm_bf16<128, 64, M_QKV, 1><<<dim3(48, 16), b256, 0, stream>>>(
        hB, nullptr, qkvT, nullptr, sa_qkv_b, nullptr, nullptr,
        nullptr, Qb, Kb, VTb, KsumP, 3072, 1024);
    ksum_fold_kernel<<<dim3(8), b256, 0, stream>>>(KsumP, Ksum);
    denom_kernel<<<dim3(1024), b256, 0, stream>>>(Qb, Ksum, den);
    rope_kernel<<<dim3(512), b256, 0, stream>>>(Qb, cosT, sinT);
    rope_kernel<<<dim3(512), b256, 0, stream>>>(Kb, cosT, sinT);
    attn_mfma<<<dim3(16, 32), b256, 0, stream>>>(Qb, Kb, VTb, den, h2B, 1);
    gemm_bf16<64, 64, M_PART, 2><<<dim3(16, 32, 2), b256, 0, stream>>>(
        h2B, nullptr, prT, nullptr, nullptr, nullptr, nullptr,
        Pbuf, nullptr, nullptr, nullptr, nullptr, 1024, 1024);
    reduce_res_kernel<2><<<dim3(TOT4 / 256), b256, 0, stream>>>(Pbuf, sa_pr_b, x, out, 1024, TOT4);

    // ---- cross-attention ----
    ln_kernel<<<dim3(MM), b256, 0, stream>>>(out, ln2_g, ln2_b, hB);
    gemm_bf16<128, 64, M_CAQKV, 1><<<dim3(48, 16), b256, 0, stream>>>(
        hB, memB, caqT, cakvT, ca_q_b, ca_kv_b, nullptr,
        nullptr, Qb, Kb, VTb, KsumP, 3072, 1024);
    ksum_fold_kernel<<<dim3(8), b256, 0, stream>>>(KsumP, Ksum);
    denom_kernel<<<dim3(1024), b256, 0, stream>>>(Qb, Ksum, den);
    rope_kernel<<<dim3(512), b256, 0, stream>>>(Qb, cosT, sinT);
    rope_kernel<<<dim3(512), b256, 0, stream>>>(Kb, cosT, sinT);
    attn_mfma<<<dim3(16, 32), b256, 0, stream>>>(Qb, Kb, VTb, den, h2B, 0);
    gemm_bf16<64, 64, M_PART, 2><<<dim3(16, 32, 2), b256, 0, stream>>>(
        h2B, nullptr, caprT, nullptr, nullptr, nullptr, nullptr,
        Pbuf, nullptr, nullptr, nullptr, nullptr, 1024, 1024);
    reduce_res_kernel<2><<<dim3(TOT4 / 256), b256, 0, stream>>>(Pbuf, ca_pr_b, out, out, 1024, TOT4);

    // ---- MLP ----
    ln_kernel<<<dim3(MM), b256, 0, stream>>>(out, ln3_g, ln3_b, hB);
    gemm_bf16<128, 64, M_GELU, 1><<<dim3(64, 16), b256, 0, stream>>>(
        hB, nullptr, fcT, nullptr, fc_b, nullptr, nullptr,
        nullptr, fcB, nullptr, nullptr, nullptr, 4096, 1024);
    gemm_bf16<64, 64, M_PART, 2><<<dim3(16, 32, 2), b256, 0, stream>>>(
        fcB, nullptr, fcpT, nullptr, nullptr, nullptr, nullptr,
        Pbuf, nullptr, nullptr, nullptr, nullptr, 1024, 4096);
    reduce_res_kernel<2><<<dim3(TOT4 / 256), b256, 0, stream>>>(Pbuf, fcp_b, out, out, 1024, TOT4);
}